// Round 12
// baseline (165.003 us; speedup 1.0000x reference)
//
#include <hip/hip_runtime.h>
#include <stdint.h>

typedef __bf16 bf16;
typedef __bf16 bf16x8 __attribute__((ext_vector_type(8)));
typedef __bf16 bf16x4 __attribute__((ext_vector_type(4)));
typedef float f32x4 __attribute__((ext_vector_type(4)));

constexpr int nB = 2, nS = 2048, nD = 768, nH = 12, nDK = 64;
constexpr int nM = nB * nS;  // 4096
constexpr float LN_EPS = 1e-5f;

static __device__ __forceinline__ f32x4 mfma16(bf16x8 a, bf16x8 b, f32x4 c) {
  return __builtin_amdgcn_mfma_f32_16x16x32_bf16(a, b, c, 0, 0, 0);
}

static __device__ __forceinline__ void gll16(const void* g, void* l) {
  __builtin_amdgcn_global_load_lds(
      (const __attribute__((address_space(1))) void*)g,
      (__attribute__((address_space(3))) void*)l, 16, 0, 0);
}

// ---------------- prep: x -> bf16 ----------------
__global__ __launch_bounds__(256) void k_prep_x(const float* __restrict__ x,
                                                bf16* __restrict__ xb) {
  int i = (blockIdx.x * 256 + threadIdx.x) * 4;
  float4 v = *(const float4*)(x + i);
  bf16x4 o;
  o[0] = (bf16)v.x; o[1] = (bf16)v.y; o[2] = (bf16)v.z; o[3] = (bf16)v.w;
  *(bf16x4*)(xb + i) = o;
}

// ---------------- prep: weights -> bf16, transposed to [n][k] ----------------
__global__ __launch_bounds__(256) void k_prep_w(
    const float* __restrict__ w0, const float* __restrict__ w1,
    const float* __restrict__ w2, const float* __restrict__ w3,
    const float* __restrict__ w4, bf16* __restrict__ wt) {
  __shared__ float tb[64][65];
  int w = blockIdx.z;
  const float* src = (w == 0) ? w0 : (w == 1) ? w1 : (w == 2) ? w2 : (w == 3) ? w3 : w4;
  int k0 = blockIdx.y * 64, n0 = blockIdx.x * 64;
  int tx = threadIdx.x & 63, ty = threadIdx.x >> 6;
#pragma unroll
  for (int it = 0; it < 16; ++it) {
    int r = it * 4 + ty;
    tb[r][tx] = src[(size_t)(k0 + r) * nD + n0 + tx];
  }
  __syncthreads();
  bf16* dst = wt + (size_t)w * nD * nD;
#pragma unroll
  for (int it = 0; it < 16; ++it) {
    int r = it * 4 + ty;
    dst[(size_t)(n0 + r) * nD + k0 + tx] = (bf16)tb[tx][r];
  }
}

// ---------------- QPKV GEMM: C = X @ W (Wt is W^T), 128x128 tile, BK=64 ----------------
__global__ __launch_bounds__(256, 2) void k_gemm_qpkv(
    const bf16* __restrict__ xb, const bf16* __restrict__ wt,
    bf16* __restrict__ qf, bf16* __restrict__ pf, bf16* __restrict__ kf_,
    bf16* __restrict__ vt) {
  __shared__ alignas(16) char smem[65536];  // [2 bufs][A 16K | B 16K]
  int t = threadIdx.x, lane = t & 63, w = t >> 6;
  int fr = lane & 15, fg = lane >> 4;
  int wm = w >> 1, wn = w & 1;
  int widx = blockIdx.z;
  int m0 = blockIdx.y * 128, n0 = blockIdx.x * 128;
  const bf16* abase = xb + (size_t)m0 * nD;
  const bf16* bbase = wt + (size_t)widx * nD * nD + (size_t)n0 * nD;

  f32x4 acc[4][4];
#pragma unroll
  for (int i = 0; i < 4; ++i)
#pragma unroll
    for (int j = 0; j < 4; ++j) acc[i][j] = (f32x4){0.f, 0.f, 0.f, 0.f};

  int aoff[2][4], boff[2][4];
#pragma unroll
  for (int ks = 0; ks < 2; ++ks) {
#pragma unroll
    for (int i = 0; i < 4; ++i) {
      int row = wm * 64 + i * 16 + fr;
      aoff[ks][i] = row * 128 + (((ks * 4 + fg) ^ (row & 7)) << 4);
      int rowb = wn * 64 + i * 16 + fr;
      boff[ks][i] = 16384 + rowb * 128 + (((ks * 4 + fg) ^ (rowb & 7)) << 4);
    }
  }
  const bf16 *asrc[4], *bsrc[4];
#pragma unroll
  for (int i = 0; i < 4; ++i) {
    int row = i * 32 + (t >> 3);
    int c = (t & 7) ^ (row & 7);
    asrc[i] = abase + (size_t)row * nD + c * 8;
    bsrc[i] = bbase + (size_t)row * nD + c * 8;
  }

#define STAGEG(BUF, kt)                                                        \
  {                                                                            \
    _Pragma("unroll") for (int i = 0; i < 4; ++i) {                            \
      gll16(asrc[i] + (kt)*64, smem + (BUF) + i * 4096 + w * 1024);            \
      gll16(bsrc[i] + (kt)*64, smem + (BUF) + 16384 + i * 4096 + w * 1024);    \
    }                                                                          \
  }

#define COMPUTEG(BUF)                                                          \
  {                                                                            \
    _Pragma("unroll") for (int ks = 0; ks < 2; ++ks) {                         \
      bf16x8 af[4], bfr[4];                                                    \
      _Pragma("unroll") for (int i = 0; i < 4; ++i)                            \
          af[i] = *(const bf16x8*)(smem + (BUF) + aoff[ks][i]);                \
      _Pragma("unroll") for (int j = 0; j < 4; ++j)                            \
          bfr[j] = *(const bf16x8*)(smem + (BUF) + boff[ks][j]);               \
      _Pragma("unroll") for (int i = 0; i < 4; ++i)                            \
          _Pragma("unroll") for (int j = 0; j < 4; ++j) acc[i][j] =            \
          mfma16(af[i], bfr[j], acc[i][j]);                                    \
    }                                                                          \
  }

  STAGEG(0, 0);
  __syncthreads();
#pragma unroll 1
  for (int kt = 0; kt < 12; kt += 2) {
    if (kt + 1 < 12) STAGEG(32768, kt + 1);
    COMPUTEG(0);
    __syncthreads();
    if (kt + 2 < 12) STAGEG(0, kt + 2);
    COMPUTEG(32768);
    __syncthreads();
  }
#undef STAGEG
#undef COMPUTEG

  if (widx < 3) {
    bf16* outf = (widx == 0) ? qf : (widx == 1) ? pf : kf_;
    float oscale = (widx == 2) ? 0.18033688f : 1.0f;  // K: DK^-0.5 * log2(e)
#pragma unroll
    for (int i = 0; i < 4; ++i)
#pragma unroll
      for (int j = 0; j < 4; ++j) {
        int n = n0 + wn * 64 + j * 16 + fr;
#pragma unroll
        for (int r = 0; r < 4; ++r) {
          int m = m0 + wm * 64 + i * 16 + fg * 4 + r;
          outf[(size_t)m * nD + n] = (bf16)(acc[i][j][r] * oscale);
        }
      }
  } else {
#pragma unroll
    for (int i = 0; i < 4; ++i)
#pragma unroll
      for (int j = 0; j < 4; ++j) {
        int n = n0 + wn * 64 + j * 16 + fr;
        int h = n >> 6, dk = n & 63;
        int mbase = m0 + wm * 64 + i * 16 + fg * 4;
        int b = mbase >> 11, s = mbase & (nS - 1);
        int bh = b * nH + h;
        bf16x4 pk;
#pragma unroll
        for (int r = 0; r < 4; ++r) pk[r] = (bf16)acc[i][j][r];
        *(bf16x4*)(vt + ((size_t)bh * nDK + dk) * nS + s) = pk;
      }
  }
}

// ---------------- attention pass 1 + leapfrog -> q_new ----------------
// R10 structure (4 waves x 16 q, 64-key tiles, hoisted offsets, counted
// vmcnt, unnormalized exp2 softmax + ones-MFMA row-sum) with V SOURCED FROM
// GLOBAL into registers: V is read-only and L1/L2-resident (8KB/tile shared
// by all 4 waves; 256KB/bh shared by 32 blocks), so the V LDS round-trip
// (staging + 8 b128 reads/tile) is deleted. LDS traffic per wave-tile drops
// 264->~144 cyc; V moves to the idle TA/L1 pipe; no barrier needed for V.
// K staging halves to 2 gll16/wave -> counted wait vmcnt(10)
// (K_cur 2 oldest + V 8 + K_next 2 outstanding).
__global__ __launch_bounds__(256, 3) void k_attn(
    const bf16* __restrict__ qf, const bf16* __restrict__ pf,
    const bf16* __restrict__ kf_, const bf16* __restrict__ vt,
    const float* __restrict__ dtp, const float* __restrict__ gatep,
    bf16* __restrict__ qn) {
  // LDS: K dbuf @0/@8192 | P 4x2KB @16384  = 24KB
  __shared__ alignas(16) char lds[24576];
  int t = threadIdx.x, lane = t & 63, w = t >> 6;
  int fr = lane & 15, fg = lane >> 4;
  int blk = blockIdx.x;
  int qt = blk & 31, bh = blk >> 5;
  int b = bh / nH, h = bh % nH;
  int q0 = qt * 64 + w * 16;
  const bf16* Qrow = qf + (size_t)(b * nS) * nD + (size_t)h * nDK;
  const bf16* Prow = pf + (size_t)(b * nS) * nD + (size_t)h * nDK;
  const bf16* Krow = kf_ + (size_t)(b * nS) * nD + (size_t)h * nDK;
  const bf16* Vb = vt + (size_t)bh * nDK * nS;
  char* myp = lds + 16384 + w * 2048;

  bf16x8 qa[2];
#pragma unroll
  for (int ks = 0; ks < 2; ++ks)
    qa[ks] = *(const bf16x8*)(Qrow + (size_t)(q0 + fr) * nD + ks * 32 + fg * 8);

  // all-ones A-fragment for the MFMA row-sum (softmax denominator)
  bf16x8 vone;
#pragma unroll
  for (int i = 0; i < 8; ++i) vone[i] = (bf16)1.0f;

  f32x4 o[5];  // o[0..3]: O^T[dv=df*16+fg*4+r][q=fr]; o[4]: row-sum lr
#pragma unroll
  for (int df = 0; df < 5; ++df) o[df] = (f32x4){0.f, 0.f, 0.f, 0.f};

  // ---- hoisted LDS offsets (loop-invariant) ----
  int koA[4], koB[4];
#pragma unroll
  for (int kfi = 0; kfi < 4; ++kfi) {
    int key = kfi * 16 + fr;
    koA[kfi] = key * 128 + ((fg ^ (key & 7)) << 4);
    koB[kfi] = key * 128 + (((4 + fg) ^ (key & 7)) << 4);
  }
  int pr[2], pw[4];
#pragma unroll
  for (int ks = 0; ks < 2; ++ks)
    pr[ks] = fr * 128 + (((ks * 4 + fg) ^ (fr & 7)) << 4);
#pragma unroll
  for (int kfi = 0; kfi < 4; ++kfi) {
    int blk16 = kfi * 2 + (fg >> 1);
    pw[kfi] = fr * 128 + (((blk16 ^ (fr & 7)) << 4) | ((fg & 1) << 3));
  }

  // ---- V global fragment bases (per df); tile adds kt*64 elements ----
  const bf16* vptr[4];
#pragma unroll
  for (int df = 0; df < 4; ++df)
    vptr[df] = Vb + (size_t)(df * 16 + fr) * nS + fg * 8;

  // ---- K staging sources (pre-swizzled; involution with read XOR) ----
  const bf16 *ks0, *ks1;
  {
    int r0 = w * 16 + (lane >> 3), c0 = (lane & 7) ^ (r0 & 7);
    int r1 = r0 + 8, c1 = (lane & 7) ^ (r1 & 7);
    ks0 = Krow + (size_t)r0 * nD + c0 * 8;
    ks1 = Krow + (size_t)r1 * nD + c1 * 8;
  }

#define STAGE(KB, kt)                                                          \
  {                                                                            \
    gll16(ks0 + (size_t)(kt)*64 * nD, lds + (KB) + w * 2048);                  \
    gll16(ks1 + (size_t)(kt)*64 * nD, lds + (KB) + w * 2048 + 1024);           \
  }

#define VLOAD(VV, kt)                                                          \
  {                                                                            \
    _Pragma("unroll") for (int df = 0; df < 4; ++df) {                         \
      VV[0][df] = *(const bf16x8*)(vptr[df] + (kt)*64);                        \
      VV[1][df] = *(const bf16x8*)(vptr[df] + (kt)*64 + 32);                   \
    }                                                                          \
  }

#define COMPUTE(KB, VV)                                                        \
  {                                                                            \
    f32x4 sf[4];                                                               \
    _Pragma("unroll") for (int kfi = 0; kfi < 4; ++kfi) {                      \
      bf16x8 ka = *(const bf16x8*)(lds + (KB) + koA[kfi]);                     \
      bf16x8 kc = *(const bf16x8*)(lds + (KB) + koB[kfi]);                     \
      f32x4 s = mfma16(ka, qa[0], (f32x4){0.f, 0.f, 0.f, 0.f});                \
      sf[kfi] = mfma16(kc, qa[1], s);                                          \
    }                                                                          \
    _Pragma("unroll") for (int kfi = 0; kfi < 4; ++kfi) {                      \
      bf16x4 pk;                                                               \
      _Pragma("unroll") for (int r = 0; r < 4; ++r)                            \
          pk[r] = (bf16)__builtin_exp2f(sf[kfi][r]);                           \
      *(bf16x4*)(myp + pw[kfi]) = pk;                                          \
    }                                                                          \
    _Pragma("unroll") for (int ks = 0; ks < 2; ++ks) {                         \
      bf16x8 pb = *(const bf16x8*)(myp + pr[ks]);                              \
      _Pragma("unroll") for (int df = 0; df < 4; ++df)                         \
          o[df] = mfma16(VV[ks][df], pb, o[df]);                               \
      o[4] = mfma16(vone, pb, o[4]);                                           \
    }                                                                          \
  }

#define VMCNT10 asm volatile("s_waitcnt vmcnt(10)" ::: "memory")
#define VMCNT8 asm volatile("s_waitcnt vmcnt(8)" ::: "memory")
#define BAR __builtin_amdgcn_s_barrier()

  STAGE(0, 0);
#pragma unroll 1
  for (int kt = 0; kt < 32; kt += 2) {
    bf16x8 vA[2][4], vB[2][4];
    VLOAD(vA, kt);       // V for current tile: no barrier needed (read-only)
    STAGE(8192, kt + 1); // K prefetch stays in flight across barrier
    VMCNT10;             // retire K(kt) (oldest 2); V(8)+K_next(2) in flight
    BAR;
    COMPUTE(0, vA);
    BAR;
    VLOAD(vB, kt + 1);
    if (kt + 2 < 32) {
      STAGE(0, kt + 2);
      VMCNT10;
    } else {
      VMCNT8;
    }
    BAR;
    COMPUTE(8192, vB);
    BAR;
  }
#undef STAGE
#undef VLOAD
#undef COMPUTE
#undef VMCNT10
#undef VMCNT8
#undef BAR

  // leapfrog: q_new = q + dt*p - (dt^2/2)*gate*pe1
  float dt = dtp[0], gate = gatep[0];
  float c2 = 0.5f * dt * dt * gate;
  float inv = 1.f / o[4][0];  // lr, identical in every lane sharing this q
  int qrow = q0 + fr;
#pragma unroll
  for (int df = 0; df < 4; ++df) {
    int dk = df * 16 + fg * 4;
    bf16x4 qv4 = *(const bf16x4*)(Qrow + (size_t)qrow * nD + dk);
    bf16x4 pv4 = *(const bf16x4*)(Prow + (size_t)qrow * nD + dk);
    bf16x4 ov;
#pragma unroll
    for (int r = 0; r < 4; ++r) {
      float pe = o[df][r] * inv;
      ov[r] = (bf16)((float)qv4[r] + dt * (float)pv4[r] - c2 * pe);
    }
    *(bf16x4*)(qn + ((size_t)(b * nS) + qrow) * nD + h * nDK + dk) = ov;
  }
}

// ---------------- output GEMM: outp = qn @ Wo + bo + x (f32) ----------------
__global__ __launch_bounds__(256, 2) void k_gemm_out(
    const bf16* __restrict__ qn, const bf16* __restrict__ wto,
    const float* __restrict__ bo, const float* __restrict__ x,
    float* __restrict__ outp) {
  __shared__ alignas(16) char smem[65536];
  int t = threadIdx.x, lane = t & 63, w = t >> 6;
  int fr = lane & 15, fg = lane >> 4;
  int wm = w >> 1, wn = w & 1;
  int m0 = blockIdx.y * 128, n0 = blockIdx.x * 128;
  const bf16* abase = qn + (size_t)m0 * nD;
  const bf16* bbase = wto + (size_t)n0 * nD;

  f32x4 acc[4][4];
#pragma unroll
  for (int i = 0; i < 4; ++i)
#pragma unroll
    for (int j = 0; j < 4; ++j) acc[i][j] = (f32x4){0.f, 0.f, 0.f, 0.f};

  int aoff[2][4], boff[2][4];
#pragma unroll
  for (int ks = 0; ks < 2; ++ks) {
#pragma unroll
    for (int i = 0; i < 4; ++i) {
      int row = wm * 64 + i * 16 + fr;
      aoff[ks][i] = row * 128 + (((ks * 4 + fg) ^ (row & 7)) << 4);
      int rowb = wn * 64 + i * 16 + fr;
      boff[ks][i] = 16384 + rowb * 128 + (((ks * 4 + fg) ^ (rowb & 7)) << 4);
    }
  }
  const bf16 *asrc[4], *bsrc[4];
#pragma unroll
  for (int i = 0; i < 4; ++i) {
    int row = i * 32 + (t >> 3);
    int c = (t & 7) ^ (row & 7);
    asrc[i] = abase + (size_t)row * nD + c * 8;
    bsrc[i] = bbase + (size_t)row * nD + c * 8;
  }

#define STAGEG(BUF, kt)                                                        \
  {                                                                            \
    _Pragma("unroll") for (int i = 0; i < 4; ++i) {                            \
      gll16(asrc[i] + (kt)*64, smem + (BUF) + i * 4096 + w * 1024);            \
      gll16(bsrc[i] + (kt)*64, smem + (BUF) + 16384 + i * 4096 + w * 1024);    \
    }                                                                          \
  }

#define COMPUTEG(BUF)                                                          \
  {                                                                            \
    _Pragma("unroll") for (int ks = 0; ks < 2; ++ks) {                         \
      bf16x8 af[4], bfr[4];                                                    \
      _Pragma("unroll") for (int i = 0; i < 4; ++i)                            \
          af[i] = *(const bf16x8*)(smem + (BUF) + aoff[ks][i]);                \
      _Pragma("unroll") for (int j = 0; j < 4; ++j)                            \
          bfr[j] = *(const bf16x8*)(smem + (BUF) + boff[ks][j]);               \
      _Pragma("unroll") for (int i = 0; i < 4; ++i)                            \
          _Pragma("unroll") for (int j = 0; j < 4; ++j) acc[i][j] =            \
          mfma16(af[i], bfr[j], acc[i][j]);                                    \
    }                                                                          \
  }

  STAGEG(0, 0);
  __syncthreads();
#pragma unroll 1
  for (int kt = 0; kt < 12; kt += 2) {
    if (kt + 1 < 12) STAGEG(32768, kt + 1);
    COMPUTEG(0);
    __syncthreads();
    if (kt + 2 < 12) STAGEG(0, kt + 2);
    COMPUTEG(32768);
    __syncthreads();
  }
#undef STAGEG
#undef COMPUTEG

#pragma unroll
  for (int i = 0; i < 4; ++i)
#pragma unroll
    for (int j = 0; j < 4; ++j) {
      int n = n0 + wn * 64 + j * 16 + fr;
      float bias = bo[n];
#pragma unroll
      for (int r = 0; r < 4; ++r) {
        int m = m0 + wm * 64 + i * 16 + fg * 4 + r;
        outp[(size_t)m * nD + n] = acc[i][j][r] + bias + x[(size_t)m * nD + n];
      }
    }
}

// ---------------- LayerNorm (in-place on d_out), one wave per row ----------------
__global__ __launch_bounds__(256) void k_ln(const float* outp,
                                            const float* __restrict__ gamma,
                                            const float* __restrict__ beta,
                                            float* y) {
  int t = threadIdx.x, lane = t & 63, w = t >> 6;
  int row = blockIdx.x * 4 + w;
  const float* rp = outp + (size_t)row * nD;
  float v[12], s1 = 0.f, s2 = 0.f;
#pragma unroll
  for (int i = 0; i < 12; ++i) {
    v[i] = rp[lane + i * 64];
    s1 += v[i];
    s2 += v[i] * v[i];
  }
#pragma unroll
  for (int d = 1; d < 64; d <<= 1) {
    s1 += __shfl_xor(s1, d);
    s2 += __shfl_xor(s2, d);
  }
  float mu = s1 * (1.f / 768.f);
  float var = s2 * (1.f / 768.f) - mu * mu;
  float rstd = rsqrtf(var + LN_EPS);
  float* yp = y + (size_t)row * nD;
#pragma unroll
  for (int i = 0; i < 12; ++i) {
    int n = lane + i * 64;
    yp[n] = (v[i] - mu) * rstd * gamma[n] + beta[n];
  }
}

extern "C" void kernel_launch(void* const* d_in, const int* in_sizes, int n_in,
                              void* d_out, int out_size, void* d_ws, size_t ws_size,
                              hipStream_t stream) {
  const float* x = (const float*)d_in[0];
  const float* Wq = (const float*)d_in[1];
  const float* Wp = (const float*)d_in[2];
  const float* Wk = (const float*)d_in[3];
  const float* Wv = (const float*)d_in[4];
  const float* Wo = (const float*)d_in[5];
  const float* bo = (const float*)d_in[6];
  const float* gamma = (const float*)d_in[7];
  const float* beta = (const float*)d_in[8];
  const float* dt = (const float*)d_in[9];
  const float* gate = (const float*)d_in[10];

  char* ws = (char*)d_ws;
  const size_t szb = (size_t)nM * nD * 2;  // 6,291,456 bytes per bf16 [4096][768]
  bf16* xb = (bf16*)(ws + 0 * szb);        // reused as qn after QPKV GEMM
  bf16* qf = (bf16*)(ws + 1 * szb);
  bf16* pf = (bf16*)(ws + 2 * szb);
  bf16* kf_ = (bf16*)(ws + 3 * szb);
  bf16* vt = (bf16*)(ws + 4 * szb);
  bf16* wt = (bf16*)(ws + 5 * szb);  // 5 * 768*768 bf16 = 5,898,240 bytes
  bf16* qn = xb;
  float* outp = (float*)d_out;  // out-GEMM result, LN runs in place

  k_prep_x<<<dim3(nM * nD / 1024), dim3(256), 0, stream>>>(x, xb);
  k_prep_w<<<dim3(12, 12, 5), dim3(256), 0, stream>>>(Wq, Wp, Wk, Wv, Wo, wt);
  k_gemm_qpkv<<<dim3(6, 32, 4), dim3(256), 0, stream>>>(xb, wt, qf, pf, kf_, vt);
  k_attn<<<dim3(768), dim3(256), 0, stream>>>(qf, pf, kf_, vt, dt, gate, qn);
  k_gemm_out<<<dim3(6, 32), dim3(256), 0, stream>>>(qn, wt + 4 * (size_t)nD * nD, bo, x, outp);
  k_ln<<<dim3(nM / 4), dim3(256), 0, stream>>>(outp, gamma, beta, (float*)d_out);
}

// Round 13
// 112.377 us; speedup vs baseline: 1.4683x; 1.4683x over previous
//
#include <hip/hip_runtime.h>
#include <stdint.h>

typedef __bf16 bf16;
typedef __bf16 bf16x8 __attribute__((ext_vector_type(8)));
typedef __bf16 bf16x4 __attribute__((ext_vector_type(4)));
typedef float f32x4 __attribute__((ext_vector_type(4)));

constexpr int nB = 2, nS = 2048, nD = 768, nH = 12, nDK = 64;
constexpr int nM = nB * nS;  // 4096
constexpr float LN_EPS = 1e-5f;

static __device__ __forceinline__ f32x4 mfma16(bf16x8 a, bf16x8 b, f32x4 c) {
  return __builtin_amdgcn_mfma_f32_16x16x32_bf16(a, b, c, 0, 0, 0);
}

static __device__ __forceinline__ void gll16(const void* g, void* l) {
  __builtin_amdgcn_global_load_lds(
      (const __attribute__((address_space(1))) void*)g,
      (__attribute__((address_space(3))) void*)l, 16, 0, 0);
}

// ---------------- prep: x -> bf16 ----------------
__global__ __launch_bounds__(256) void k_prep_x(const float* __restrict__ x,
                                                bf16* __restrict__ xb) {
  int i = (blockIdx.x * 256 + threadIdx.x) * 4;
  float4 v = *(const float4*)(x + i);
  bf16x4 o;
  o[0] = (bf16)v.x; o[1] = (bf16)v.y; o[2] = (bf16)v.z; o[3] = (bf16)v.w;
  *(bf16x4*)(xb + i) = o;
}

// ---------------- prep: weights -> bf16, transposed to [n][k] ----------------
__global__ __launch_bounds__(256) void k_prep_w(
    const float* __restrict__ w0, const float* __restrict__ w1,
    const float* __restrict__ w2, const float* __restrict__ w3,
    const float* __restrict__ w4, bf16* __restrict__ wt) {
  __shared__ float tb[64][65];
  int w = blockIdx.z;
  const float* src = (w == 0) ? w0 : (w == 1) ? w1 : (w == 2) ? w2 : (w == 3) ? w3 : w4;
  int k0 = blockIdx.y * 64, n0 = blockIdx.x * 64;
  int tx = threadIdx.x & 63, ty = threadIdx.x >> 6;
#pragma unroll
  for (int it = 0; it < 16; ++it) {
    int r = it * 4 + ty;
    tb[r][tx] = src[(size_t)(k0 + r) * nD + n0 + tx];
  }
  __syncthreads();
  bf16* dst = wt + (size_t)w * nD * nD;
#pragma unroll
  for (int it = 0; it < 16; ++it) {
    int r = it * 4 + ty;
    dst[(size_t)(n0 + r) * nD + k0 + tx] = (bf16)tb[tx][r];
  }
}

// ---------------- QPKV GEMM: C = X @ W (Wt is W^T), 128x128 tile, BK=64 ----------------
// 1D grid (768) with 2D XCD swizzle: xcd&3 selects a group of 6 (n,widx)
// panels, xcd>>2 selects a y-half -> each B-panel lives in 2 XCD L2s, each
// A y-half in 4, cutting HBM re-fetch ~2x. All offsets hoisted (R10).
__global__ __launch_bounds__(256, 2) void k_gemm_qpkv(
    const bf16* __restrict__ xb, const bf16* __restrict__ wt,
    bf16* __restrict__ qf, bf16* __restrict__ pf, bf16* __restrict__ kf_,
    bf16* __restrict__ vt) {
  __shared__ alignas(16) char smem[65536];  // [2 bufs][A 16K | B 16K]
  int t = threadIdx.x, lane = t & 63, w = t >> 6;
  int fr = lane & 15, fg = lane >> 4;
  int wm = w >> 1, wn = w & 1;
  // XCD-aware decode: p%8 = physical XCD (round-robin dispatch)
  int p = blockIdx.x;
  int xcd = p & 7, slot = p >> 3;          // slot 0..95
  int combo = (xcd & 3) * 6 + (slot >> 4); // 0..23 = (n-col, widx)
  int yy = (xcd >> 2) * 16 + (slot & 15);  // 0..31 = m-row block
  int xx = combo % 6, widx = combo / 6;
  int m0 = yy * 128, n0 = xx * 128;
  const bf16* abase = xb + (size_t)m0 * nD;
  const bf16* bbase = wt + (size_t)widx * nD * nD + (size_t)n0 * nD;

  f32x4 acc[4][4];
#pragma unroll
  for (int i = 0; i < 4; ++i)
#pragma unroll
    for (int j = 0; j < 4; ++j) acc[i][j] = (f32x4){0.f, 0.f, 0.f, 0.f};

  int aoff[2][4], boff[2][4];
#pragma unroll
  for (int ks = 0; ks < 2; ++ks) {
#pragma unroll
    for (int i = 0; i < 4; ++i) {
      int row = wm * 64 + i * 16 + fr;
      aoff[ks][i] = row * 128 + (((ks * 4 + fg) ^ (row & 7)) << 4);
      int rowb = wn * 64 + i * 16 + fr;
      boff[ks][i] = 16384 + rowb * 128 + (((ks * 4 + fg) ^ (rowb & 7)) << 4);
    }
  }
  const bf16 *asrc[4], *bsrc[4];
#pragma unroll
  for (int i = 0; i < 4; ++i) {
    int row = i * 32 + (t >> 3);
    int c = (t & 7) ^ (row & 7);
    asrc[i] = abase + (size_t)row * nD + c * 8;
    bsrc[i] = bbase + (size_t)row * nD + c * 8;
  }

#define STAGEG(BUF, kt)                                                        \
  {                                                                            \
    _Pragma("unroll") for (int i = 0; i < 4; ++i) {                            \
      gll16(asrc[i] + (kt)*64, smem + (BUF) + i * 4096 + w * 1024);            \
      gll16(bsrc[i] + (kt)*64, smem + (BUF) + 16384 + i * 4096 + w * 1024);    \
    }                                                                          \
  }

#define COMPUTEG(BUF)                                                          \
  {                                                                            \
    _Pragma("unroll") for (int ks = 0; ks < 2; ++ks) {                         \
      bf16x8 af[4], bfr[4];                                                    \
      _Pragma("unroll") for (int i = 0; i < 4; ++i)                            \
          af[i] = *(const bf16x8*)(smem + (BUF) + aoff[ks][i]);                \
      _Pragma("unroll") for (int j = 0; j < 4; ++j)                            \
          bfr[j] = *(const bf16x8*)(smem + (BUF) + boff[ks][j]);               \
      _Pragma("unroll") for (int i = 0; i < 4; ++i)                            \
          _Pragma("unroll") for (int j = 0; j < 4; ++j) acc[i][j] =            \
          mfma16(af[i], bfr[j], acc[i][j]);                                    \
    }                                                                          \
  }

  STAGEG(0, 0);
  __syncthreads();
#pragma unroll 1
  for (int kt = 0; kt < 12; kt += 2) {
    if (kt + 1 < 12) STAGEG(32768, kt + 1);
    COMPUTEG(0);
    __syncthreads();
    if (kt + 2 < 12) STAGEG(0, kt + 2);
    COMPUTEG(32768);
    __syncthreads();
  }
#undef STAGEG
#undef COMPUTEG

  if (widx < 3) {
    bf16* outf = (widx == 0) ? qf : (widx == 1) ? pf : kf_;
    float oscale = (widx == 2) ? 0.18033688f : 1.0f;  // K: DK^-0.5 * log2(e)
#pragma unroll
    for (int i = 0; i < 4; ++i)
#pragma unroll
      for (int j = 0; j < 4; ++j) {
        int n = n0 + wn * 64 + j * 16 + fr;
#pragma unroll
        for (int r = 0; r < 4; ++r) {
          int m = m0 + wm * 64 + i * 16 + fg * 4 + r;
          outf[(size_t)m * nD + n] = (bf16)(acc[i][j][r] * oscale);
        }
      }
  } else {
#pragma unroll
    for (int i = 0; i < 4; ++i)
#pragma unroll
      for (int j = 0; j < 4; ++j) {
        int n = n0 + wn * 64 + j * 16 + fr;
        int h = n >> 6, dk = n & 63;
        int mbase = m0 + wm * 64 + i * 16 + fg * 4;
        int b = mbase >> 11, s = mbase & (nS - 1);
        int bh = b * nH + h;
        bf16x4 pk;
#pragma unroll
        for (int r = 0; r < 4; ++r) pk[r] = (bf16)acc[i][j][r];
        *(bf16x4*)(vt + ((size_t)bh * nDK + dk) * nS + s) = pk;
      }
  }
}

// ---------------- attention pass 1 + leapfrog -> q_new ----------------
// R10 structure (4 waves x 16 q, 64-key LDS-staged tiles, hoisted offsets,
// counted vmcnt(4), unnormalized exp2 softmax + ones-MFMA row-sum) + XCD
// swizzle: all 32 q-tiles of one (b,h) land on ONE XCD, so its K/V head
// (512KB) is fetched into one L2 instead of ~8 -> FETCH_SIZE ~58->~20MB.
__global__ __launch_bounds__(256, 3) void k_attn(
    const bf16* __restrict__ qf, const bf16* __restrict__ pf,
    const bf16* __restrict__ kf_, const bf16* __restrict__ vt,
    const float* __restrict__ dtp, const float* __restrict__ gatep,
    bf16* __restrict__ qn) {
  // LDS: K dbuf @0/@8192 | V dbuf @16384/@24576 | P 4x2KB @32768  = 40KB
  __shared__ alignas(16) char lds[40960];
  int t = threadIdx.x, lane = t & 63, w = t >> 6;
  int fr = lane & 15, fg = lane >> 4;
  // XCD-aware decode: consecutive physical blocks round-robin XCDs (p%8);
  // give each XCD whole bh's: bh = xcd + 8*(slot/32), qt = slot%32.
  int p = blockIdx.x;
  int xcd = p & 7, slot = p >> 3;
  int qt = slot & 31, bh = xcd + 8 * (slot >> 5);
  int b = bh / nH, h = bh % nH;
  int q0 = qt * 64 + w * 16;
  const bf16* Qrow = qf + (size_t)(b * nS) * nD + (size_t)h * nDK;
  const bf16* Prow = pf + (size_t)(b * nS) * nD + (size_t)h * nDK;
  const bf16* Krow = kf_ + (size_t)(b * nS) * nD + (size_t)h * nDK;
  const bf16* Vb = vt + (size_t)bh * nDK * nS;
  char* myp = lds + 32768 + w * 2048;

  bf16x8 qa[2];
#pragma unroll
  for (int ks = 0; ks < 2; ++ks)
    qa[ks] = *(const bf16x8*)(Qrow + (size_t)(q0 + fr) * nD + ks * 32 + fg * 8);

  // all-ones A-fragment: MFMA row-sum accumulator operand (no LDS needed)
  bf16x8 vone;
#pragma unroll
  for (int i = 0; i < 8; ++i) vone[i] = (bf16)1.0f;

  f32x4 o[5];  // o[0..3]: O^T[dv=df*16+fg*4+r][q=fr]; o[4]: row-sum lr
#pragma unroll
  for (int df = 0; df < 5; ++df) o[df] = (f32x4){0.f, 0.f, 0.f, 0.f};

  // ---- hoisted LDS read/write offsets (bytes, loop-invariant) ----
  int koA[4], koB[4];
#pragma unroll
  for (int kfi = 0; kfi < 4; ++kfi) {
    int key = kfi * 16 + fr;
    koA[kfi] = key * 128 + ((fg ^ (key & 7)) << 4);
    koB[kfi] = key * 128 + (((4 + fg) ^ (key & 7)) << 4);
  }
  int vo[2][4], pr[2], pw[4];
#pragma unroll
  for (int ks = 0; ks < 2; ++ks) {
    pr[ks] = fr * 128 + (((ks * 4 + fg) ^ (fr & 7)) << 4);
#pragma unroll
    for (int df = 0; df < 4; ++df) {
      int row = df * 16 + fr;
      vo[ks][df] = row * 128 + (((ks * 4 + fg) ^ (row & 7)) << 4);
    }
  }
#pragma unroll
  for (int kfi = 0; kfi < 4; ++kfi) {
    int blk16 = kfi * 2 + (fg >> 1);
    pw[kfi] = fr * 128 + (((blk16 ^ (fr & 7)) << 4) | ((fg & 1) << 3));
  }

  // ---- hoisted staging sources (pre-swizzled; involution with read XOR) ----
  const bf16 *ks0, *ks1, *vs0, *vs1;
  {
    int r0 = w * 16 + (lane >> 3), c0 = (lane & 7) ^ (r0 & 7);
    int r1 = r0 + 8, c1 = (lane & 7) ^ (r1 & 7);
    ks0 = Krow + (size_t)r0 * nD + c0 * 8;
    ks1 = Krow + (size_t)r1 * nD + c1 * 8;
    vs0 = Vb + (size_t)r0 * nS + c0 * 8;
    vs1 = Vb + (size_t)r1 * nS + c1 * 8;
  }

#define STAGE(KB, VB, kt)                                                      \
  {                                                                            \
    gll16(ks0 + (size_t)(kt)*64 * nD, lds + (KB) + w * 2048);                  \
    gll16(vs0 + (kt)*64, lds + (VB) + w * 2048);                               \
    gll16(ks1 + (size_t)(kt)*64 * nD, lds + (KB) + w * 2048 + 1024);           \
    gll16(vs1 + (kt)*64, lds + (VB) + w * 2048 + 1024);                        \
  }

#define COMPUTE(KB, VB)                                                        \
  {                                                                            \
    f32x4 sf[4];                                                               \
    _Pragma("unroll") for (int kfi = 0; kfi < 4; ++kfi) {                      \
      bf16x8 ka = *(const bf16x8*)(lds + (KB) + koA[kfi]);                     \
      bf16x8 kc = *(const bf16x8*)(lds + (KB) + koB[kfi]);                     \
      f32x4 s = mfma16(ka, qa[0], (f32x4){0.f, 0.f, 0.f, 0.f});                \
      sf[kfi] = mfma16(kc, qa[1], s);                                          \
    }                                                                          \
    _Pragma("unroll") for (int kfi = 0; kfi < 4; ++kfi) {                      \
      bf16x4 pk;                                                               \
      _Pragma("unroll") for (int r = 0; r < 4; ++r)                            \
          pk[r] = (bf16)__builtin_exp2f(sf[kfi][r]);                           \
      *(bf16x4*)(myp + pw[kfi]) = pk;                                          \
    }                                                                          \
    _Pragma("unroll") for (int ks = 0; ks < 2; ++ks) {                         \
      bf16x8 pb = *(const bf16x8*)(myp + pr[ks]);                              \
      _Pragma("unroll") for (int df = 0; df < 4; ++df) {                       \
        bf16x8 vv = *(const bf16x8*)(lds + (VB) + vo[ks][df]);                 \
        o[df] = mfma16(vv, pb, o[df]);                                         \
      }                                                                        \
      o[4] = mfma16(vone, pb, o[4]);                                           \
    }                                                                          \
  }

#define VMCNT4 asm volatile("s_waitcnt vmcnt(4)" ::: "memory")
#define VMCNT0 asm volatile("s_waitcnt vmcnt(0)" ::: "memory")
#define BAR __builtin_amdgcn_s_barrier()

  STAGE(0, 16384, 0);
#pragma unroll 1
  for (int kt = 0; kt < 32; kt += 2) {
    STAGE(8192, 24576, kt + 1);  // prefetch stays in flight across barrier
    VMCNT4;                      // wait current buf's 4 loads only
    BAR;
    COMPUTE(0, 16384);
    BAR;
    if (kt + 2 < 32) {
      STAGE(0, 16384, kt + 2);
      VMCNT4;
    } else {
      VMCNT0;
    }
    BAR;
    COMPUTE(8192, 24576);
    BAR;
  }
#undef STAGE
#undef COMPUTE
#undef VMCNT4
#undef VMCNT0
#undef BAR

  // leapfrog: q_new = q + dt*p - (dt^2/2)*gate*pe1
  float dt = dtp[0], gate = gatep[0];
  float c2 = 0.5f * dt * dt * gate;
  float inv = 1.f / o[4][0];  // lr, identical in every lane sharing this q
  int qrow = q0 + fr;
#pragma unroll
  for (int df = 0; df < 4; ++df) {
    int dk = df * 16 + fg * 4;
    bf16x4 qv4 = *(const bf16x4*)(Qrow + (size_t)qrow * nD + dk);
    bf16x4 pv4 = *(const bf16x4*)(Prow + (size_t)qrow * nD + dk);
    bf16x4 ov;
#pragma unroll
    for (int r = 0; r < 4; ++r) {
      float pe = o[df][r] * inv;
      ov[r] = (bf16)((float)qv4[r] + dt * (float)pv4[r] - c2 * pe);
    }
    *(bf16x4*)(qn + ((size_t)(b * nS) + qrow) * nD + h * nDK + dk) = ov;
  }
}

// ---------------- output GEMM: outp = qn @ Wo + bo + x (f32) ----------------
__global__ __launch_bounds__(256, 2) void k_gemm_out(
    const bf16* __restrict__ qn, const bf16* __restrict__ wto,
    const float* __restrict__ bo, const float* __restrict__ x,
    float* __restrict__ outp) {
  __shared__ alignas(16) char smem[65536];
  int t = threadIdx.x, lane = t & 63, w = t >> 6;
  int fr = lane & 15, fg = lane >> 4;
  int wm = w >> 1, wn = w & 1;
  int m0 = blockIdx.y * 128, n0 = blockIdx.x * 128;
  const bf16* abase = qn + (size_t)m0 * nD;
  const bf16* bbase = wto + (size_t)n0 * nD;

  f32x4 acc[4][4];
#pragma unroll
  for (int i = 0; i < 4; ++i)
#pragma unroll
    for (int j = 0; j < 4; ++j) acc[i][j] = (f32x4){0.f, 0.f, 0.f, 0.f};

  int aoff[2][4], boff[2][4];
#pragma unroll
  for (int ks = 0; ks < 2; ++ks) {
#pragma unroll
    for (int i = 0; i < 4; ++i) {
      int row = wm * 64 + i * 16 + fr;
      aoff[ks][i] = row * 128 + (((ks * 4 + fg) ^ (row & 7)) << 4);
      int rowb = wn * 64 + i * 16 + fr;
      boff[ks][i] = 16384 + rowb * 128 + (((ks * 4 + fg) ^ (rowb & 7)) << 4);
    }
  }
  const bf16 *asrc[4], *bsrc[4];
#pragma unroll
  for (int i = 0; i < 4; ++i) {
    int row = i * 32 + (t >> 3);
    int c = (t & 7) ^ (row & 7);
    asrc[i] = abase + (size_t)row * nD + c * 8;
    bsrc[i] = bbase + (size_t)row * nD + c * 8;
  }

#define STAGEG(BUF, kt)                                                        \
  {                                                                            \
    _Pragma("unroll") for (int i = 0; i < 4; ++i) {                            \
      gll16(asrc[i] + (kt)*64, smem + (BUF) + i * 4096 + w * 1024);            \
      gll16(bsrc[i] + (kt)*64, smem + (BUF) + 16384 + i * 4096 + w * 1024);    \
    }                                                                          \
  }

#define COMPUTEG(BUF)                                                          \
  {                                                                            \
    _Pragma("unroll") for (int ks = 0; ks < 2; ++ks) {                         \
      bf16x8 af[4], bfr[4];                                                    \
      _Pragma("unroll") for (int i = 0; i < 4; ++i)                            \
          af[i] = *(const bf16x8*)(smem + (BUF) + aoff[ks][i]);                \
      _Pragma("unroll") for (int j = 0; j < 4; ++j)                            \
          bfr[j] = *(const bf16x8*)(smem + (BUF) + boff[ks][j]);               \
      _Pragma("unroll") for (int i = 0; i < 4; ++i)                            \
          _Pragma("unroll") for (int j = 0; j < 4; ++j) acc[i][j] =            \
          mfma16(af[i], bfr[j], acc[i][j]);                                    \
    }                                                                          \
  }

  STAGEG(0, 0);
  __syncthreads();
#pragma unroll 1
  for (int kt = 0; kt < 12; kt += 2) {
    if (kt + 1 < 12) STAGEG(32768, kt + 1);
    COMPUTEG(0);
    __syncthreads();
    if (kt + 2 < 12) STAGEG(0, kt + 2);
    COMPUTEG(32768);
    __syncthreads();
  }
#undef STAGEG
#undef COMPUTEG

#pragma unroll
  for (int i = 0; i < 4; ++i)
#pragma unroll
    for (int j = 0; j < 4; ++j) {
      int n = n0 + wn * 64 + j * 16 + fr;
      float bias = bo[n];
#pragma unroll
      for (int r = 0; r < 4; ++r) {
        int m = m0 + wm * 64 + i * 16 + fg * 4 + r;
        outp[(size_t)m * nD + n] = acc[i][j][r] + bias + x[(size_t)m * nD + n];
      }
    }
}

// ---------------- LayerNorm (in-place on d_out), one wave per row ----------------
__global__ __launch_bounds__(256) void k_ln(const float* outp,
                                            const float* __restrict__ gamma,
                                            const float* __restrict__ beta,
                                            float* y) {
  int t = threadIdx.x, lane = t & 63, w = t >> 6;
  int row = blockIdx.x * 4 + w;
  const float* rp = outp + (size_t)row * nD;
  float v[12], s1 = 0.f, s2 = 0.f;
#pragma unroll
  for (int i = 0; i < 12; ++i) {
    v[i] = rp[lane + i * 64];
    s1 += v[i];
    s2 += v[i] * v[i];
  }
#pragma unroll
  for (int d = 1; d < 64; d <<= 1) {
    s1 += __shfl_xor(s1, d);
    s2 += __shfl_xor(s2, d);
  }
  float mu = s1 * (1.f / 768.f);
  float var = s2 * (1.f / 768.f) - mu * mu;
  float rstd = rsqrtf(var + LN_EPS);
  float* yp = y + (size_t)row * nD;
#pragma unroll
  for (int i = 0; i < 12; ++i) {
    int n = lane + i * 64;
    yp[n] = (v[i] - mu) * rstd * gamma[n] + beta[n];
  }
}

extern "C" void kernel_launch(void* const* d_in, const int* in_sizes, int n_in,
                              void* d_out, int out_size, void* d_ws, size_t ws_size,
                              hipStream_t stream) {
  const float* x = (const float*)d_in[0];
  const float* Wq = (const float*)d_in[1];
  const float* Wp = (const float*)d_in[2];
  const float* Wk = (const float*)d_in[3];
  const float* Wv = (const float*)d_in[4];
  const float* Wo = (const float*)d_in[5];
  const float* bo = (const float*)d_in[6];
  const float* gamma = (const float*)d_in[7];
  const float* beta = (const float*)d_in[8];
  const float* dt = (const float*)d_in[9];
  const float* gate = (const float*)d_in[10];

  char* ws = (char*)d_ws;
  const size_t szb = (size_t)nM * nD * 2;  // 6,291,456 bytes per bf16 [4096][768]
  bf16* xb = (bf16*)(ws + 0 * szb);        // reused as qn after QPKV GEMM
  bf16* qf = (bf16*)(ws + 1 * szb);
  bf16* pf = (bf16*)(ws + 2 * szb);
  bf16* kf_ = (bf16*)(ws + 3 * szb);
  bf16* vt = (bf16*)(ws + 4 * szb);
  bf16* wt = (bf16*)(ws + 5 * szb);  // 5 * 768*768 bf16 = 5,898,240 bytes
  bf16* qn = xb;
  float* outp = (float*)d_out;  // out-GEMM result, LN runs in place

  k_prep_x<<<dim3(nM * nD / 1024), dim3(256), 0, stream>>>(x, xb);
  k_prep_w<<<dim3(12, 12, 5), dim3(256), 0, stream>>>(Wq, Wp, Wk, Wv, Wo, wt);
  k_gemm_qpkv<<<dim3(768), dim3(256), 0, stream>>>(xb, wt, qf, pf, kf_, vt);
  k_attn<<<dim3(768), dim3(256), 0, stream>>>(qf, pf, kf_, vt, dt, gate, qn);
  k_gemm_out<<<dim3(6, 32), dim3(256), 0, stream>>>(qn, wt + 4 * (size_t)nD * nD, bo, x, outp);
  k_ln<<<dim3(nM / 4), dim3(256), 0, stream>>>(outp, gamma, beta, (float*)d_out);
}

// Round 14
// 110.017 us; speedup vs baseline: 1.4998x; 1.0214x over previous
//
#include <hip/hip_runtime.h>
#include <stdint.h>

typedef __bf16 bf16;
typedef __bf16 bf16x8 __attribute__((ext_vector_type(8)));
typedef __bf16 bf16x4 __attribute__((ext_vector_type(4)));
typedef __bf16 bf16x2 __attribute__((ext_vector_type(2)));
typedef float f32x4 __attribute__((ext_vector_type(4)));

constexpr int nB = 2, nS = 2048, nD = 768, nH = 12, nDK = 64;
constexpr int nM = nB * nS;  // 4096
constexpr float LN_EPS = 1e-5f;

static __device__ __forceinline__ f32x4 mfma16(bf16x8 a, bf16x8 b, f32x4 c) {
  return __builtin_amdgcn_mfma_f32_16x16x32_bf16(a, b, c, 0, 0, 0);
}

static __device__ __forceinline__ void gll16(const void* g, void* l) {
  __builtin_amdgcn_global_load_lds(
      (const __attribute__((address_space(1))) void*)g,
      (__attribute__((address_space(3))) void*)l, 16, 0, 0);
}

// ---------------- prep: x -> bf16 ----------------
__global__ __launch_bounds__(256) void k_prep_x(const float* __restrict__ x,
                                                bf16* __restrict__ xb) {
  int i = (blockIdx.x * 256 + threadIdx.x) * 4;
  float4 v = *(const float4*)(x + i);
  bf16x4 o;
  o[0] = (bf16)v.x; o[1] = (bf16)v.y; o[2] = (bf16)v.z; o[3] = (bf16)v.w;
  *(bf16x4*)(xb + i) = o;
}

// ---------------- prep: weights -> bf16, transposed to [n][k] ----------------
// Write side vectorized: bf16x2 per lane (256B per wave-op vs 128B scalar).
__global__ __launch_bounds__(256) void k_prep_w(
    const float* __restrict__ w0, const float* __restrict__ w1,
    const float* __restrict__ w2, const float* __restrict__ w3,
    const float* __restrict__ w4, bf16* __restrict__ wt) {
  __shared__ float tb[64][65];
  int w = blockIdx.z;
  const float* src = (w == 0) ? w0 : (w == 1) ? w1 : (w == 2) ? w2 : (w == 3) ? w3 : w4;
  int k0 = blockIdx.y * 64, n0 = blockIdx.x * 64;
  int tx = threadIdx.x & 63, ty = threadIdx.x >> 6;
#pragma unroll
  for (int it = 0; it < 16; ++it) {
    int r = it * 4 + ty;
    tb[r][tx] = src[(size_t)(k0 + r) * nD + n0 + tx];
  }
  __syncthreads();
  bf16* dst = wt + (size_t)w * nD * nD;
#pragma unroll
  for (int it = 0; it < 8; ++it) {
    int r2 = it * 8 + ty * 2 + (tx >> 5);
    int k2 = (tx & 31) * 2;
    bf16x2 val;
    val[0] = (bf16)tb[k2][r2];
    val[1] = (bf16)tb[k2 + 1][r2];
    *(bf16x2*)(dst + (size_t)(n0 + r2) * nD + k0 + k2) = val;
  }
}

// ---------------- QPKV GEMM: C = X @ W (Wt is W^T), 128x128 tile, BK=64 ----------------
// 1D grid (768) with 2D XCD swizzle (unchanged from R13).
__global__ __launch_bounds__(256, 2) void k_gemm_qpkv(
    const bf16* __restrict__ xb, const bf16* __restrict__ wt,
    bf16* __restrict__ qf, bf16* __restrict__ pf, bf16* __restrict__ kf_,
    bf16* __restrict__ vt) {
  __shared__ alignas(16) char smem[65536];  // [2 bufs][A 16K | B 16K]
  int t = threadIdx.x, lane = t & 63, w = t >> 6;
  int fr = lane & 15, fg = lane >> 4;
  int wm = w >> 1, wn = w & 1;
  int p = blockIdx.x;
  int xcd = p & 7, slot = p >> 3;          // slot 0..95
  int combo = (xcd & 3) * 6 + (slot >> 4); // 0..23 = (n-col, widx)
  int yy = (xcd >> 2) * 16 + (slot & 15);  // 0..31 = m-row block
  int xx = combo % 6, widx = combo / 6;
  int m0 = yy * 128, n0 = xx * 128;
  const bf16* abase = xb + (size_t)m0 * nD;
  const bf16* bbase = wt + (size_t)widx * nD * nD + (size_t)n0 * nD;

  f32x4 acc[4][4];
#pragma unroll
  for (int i = 0; i < 4; ++i)
#pragma unroll
    for (int j = 0; j < 4; ++j) acc[i][j] = (f32x4){0.f, 0.f, 0.f, 0.f};

  int aoff[2][4], boff[2][4];
#pragma unroll
  for (int ks = 0; ks < 2; ++ks) {
#pragma unroll
    for (int i = 0; i < 4; ++i) {
      int row = wm * 64 + i * 16 + fr;
      aoff[ks][i] = row * 128 + (((ks * 4 + fg) ^ (row & 7)) << 4);
      int rowb = wn * 64 + i * 16 + fr;
      boff[ks][i] = 16384 + rowb * 128 + (((ks * 4 + fg) ^ (rowb & 7)) << 4);
    }
  }
  const bf16 *asrc[4], *bsrc[4];
#pragma unroll
  for (int i = 0; i < 4; ++i) {
    int row = i * 32 + (t >> 3);
    int c = (t & 7) ^ (row & 7);
    asrc[i] = abase + (size_t)row * nD + c * 8;
    bsrc[i] = bbase + (size_t)row * nD + c * 8;
  }

#define STAGEG(BUF, kt)                                                        \
  {                                                                            \
    _Pragma("unroll") for (int i = 0; i < 4; ++i) {                            \
      gll16(asrc[i] + (kt)*64, smem + (BUF) + i * 4096 + w * 1024);            \
      gll16(bsrc[i] + (kt)*64, smem + (BUF) + 16384 + i * 4096 + w * 1024);    \
    }                                                                          \
  }

#define COMPUTEG(BUF)                                                          \
  {                                                                            \
    _Pragma("unroll") for (int ks = 0; ks < 2; ++ks) {                         \
      bf16x8 af[4], bfr[4];                                                    \
      _Pragma("unroll") for (int i = 0; i < 4; ++i)                            \
          af[i] = *(const bf16x8*)(smem + (BUF) + aoff[ks][i]);                \
      _Pragma("unroll") for (int j = 0; j < 4; ++j)                            \
          bfr[j] = *(const bf16x8*)(smem + (BUF) + boff[ks][j]);               \
      _Pragma("unroll") for (int i = 0; i < 4; ++i)                            \
          _Pragma("unroll") for (int j = 0; j < 4; ++j) acc[i][j] =            \
          mfma16(af[i], bfr[j], acc[i][j]);                                    \
    }                                                                          \
  }

  STAGEG(0, 0);
  __syncthreads();
#pragma unroll 1
  for (int kt = 0; kt < 12; kt += 2) {
    if (kt + 1 < 12) STAGEG(32768, kt + 1);
    COMPUTEG(0);
    __syncthreads();
    if (kt + 2 < 12) STAGEG(0, kt + 2);
    COMPUTEG(32768);
    __syncthreads();
  }
#undef STAGEG
#undef COMPUTEG

  if (widx < 3) {
    bf16* outf = (widx == 0) ? qf : (widx == 1) ? pf : kf_;
    float oscale = (widx == 2) ? 0.18033688f : 1.0f;  // K: DK^-0.5 * log2(e)
#pragma unroll
    for (int i = 0; i < 4; ++i)
#pragma unroll
      for (int j = 0; j < 4; ++j) {
        int n = n0 + wn * 64 + j * 16 + fr;
#pragma unroll
        for (int r = 0; r < 4; ++r) {
          int m = m0 + wm * 64 + i * 16 + fg * 4 + r;
          outf[(size_t)m * nD + n] = (bf16)(acc[i][j][r] * oscale);
        }
      }
  } else {
#pragma unroll
    for (int i = 0; i < 4; ++i)
#pragma unroll
      for (int j = 0; j < 4; ++j) {
        int n = n0 + wn * 64 + j * 16 + fr;
        int h = n >> 6, dk = n & 63;
        int mbase = m0 + wm * 64 + i * 16 + fg * 4;
        int b = mbase >> 11, s = mbase & (nS - 1);
        int bh = b * nH + h;
        bf16x4 pk;
#pragma unroll
        for (int r = 0; r < 4; ++r) pk[r] = (bf16)acc[i][j][r];
        *(bf16x4*)(vt + ((size_t)bh * nDK + dk) * nS + s) = pk;
      }
  }
}

// ---------------- attention pass 1 + leapfrog -> q_new (R13, unchanged) ----------------
__global__ __launch_bounds__(256, 3) void k_attn(
    const bf16* __restrict__ qf, const bf16* __restrict__ pf,
    const bf16* __restrict__ kf_, const bf16* __restrict__ vt,
    const float* __restrict__ dtp, const float* __restrict__ gatep,
    bf16* __restrict__ qn) {
  // LDS: K dbuf @0/@8192 | V dbuf @16384/@24576 | P 4x2KB @32768  = 40KB
  __shared__ alignas(16) char lds[40960];
  int t = threadIdx.x, lane = t & 63, w = t >> 6;
  int fr = lane & 15, fg = lane >> 4;
  int p = blockIdx.x;
  int xcd = p & 7, slot = p >> 3;
  int qt = slot & 31, bh = xcd + 8 * (slot >> 5);
  int b = bh / nH, h = bh % nH;
  int q0 = qt * 64 + w * 16;
  const bf16* Qrow = qf + (size_t)(b * nS) * nD + (size_t)h * nDK;
  const bf16* Prow = pf + (size_t)(b * nS) * nD + (size_t)h * nDK;
  const bf16* Krow = kf_ + (size_t)(b * nS) * nD + (size_t)h * nDK;
  const bf16* Vb = vt + (size_t)bh * nDK * nS;
  char* myp = lds + 32768 + w * 2048;

  bf16x8 qa[2];
#pragma unroll
  for (int ks = 0; ks < 2; ++ks)
    qa[ks] = *(const bf16x8*)(Qrow + (size_t)(q0 + fr) * nD + ks * 32 + fg * 8);

  bf16x8 vone;
#pragma unroll
  for (int i = 0; i < 8; ++i) vone[i] = (bf16)1.0f;

  f32x4 o[5];  // o[0..3]: O^T[dv=df*16+fg*4+r][q=fr]; o[4]: row-sum lr
#pragma unroll
  for (int df = 0; df < 5; ++df) o[df] = (f32x4){0.f, 0.f, 0.f, 0.f};

  int koA[4], koB[4];
#pragma unroll
  for (int kfi = 0; kfi < 4; ++kfi) {
    int key = kfi * 16 + fr;
    koA[kfi] = key * 128 + ((fg ^ (key & 7)) << 4);
    koB[kfi] = key * 128 + (((4 + fg) ^ (key & 7)) << 4);
  }
  int vo[2][4], pr[2], pw[4];
#pragma unroll
  for (int ks = 0; ks < 2; ++ks) {
    pr[ks] = fr * 128 + (((ks * 4 + fg) ^ (fr & 7)) << 4);
#pragma unroll
    for (int df = 0; df < 4; ++df) {
      int row = df * 16 + fr;
      vo[ks][df] = row * 128 + (((ks * 4 + fg) ^ (row & 7)) << 4);
    }
  }
#pragma unroll
  for (int kfi = 0; kfi < 4; ++kfi) {
    int blk16 = kfi * 2 + (fg >> 1);
    pw[kfi] = fr * 128 + (((blk16 ^ (fr & 7)) << 4) | ((fg & 1) << 3));
  }

  const bf16 *ks0, *ks1, *vs0, *vs1;
  {
    int r0 = w * 16 + (lane >> 3), c0 = (lane & 7) ^ (r0 & 7);
    int r1 = r0 + 8, c1 = (lane & 7) ^ (r1 & 7);
    ks0 = Krow + (size_t)r0 * nD + c0 * 8;
    ks1 = Krow + (size_t)r1 * nD + c1 * 8;
    vs0 = Vb + (size_t)r0 * nS + c0 * 8;
    vs1 = Vb + (size_t)r1 * nS + c1 * 8;
  }

#define STAGE(KB, VB, kt)                                                      \
  {                                                                            \
    gll16(ks0 + (size_t)(kt)*64 * nD, lds + (KB) + w * 2048);                  \
    gll16(vs0 + (kt)*64, lds + (VB) + w * 2048);                               \
    gll16(ks1 + (size_t)(kt)*64 * nD, lds + (KB) + w * 2048 + 1024);           \
    gll16(vs1 + (kt)*64, lds + (VB) + w * 2048 + 1024);                        \
  }

#define COMPUTE(KB, VB)                                                        \
  {                                                                            \
    f32x4 sf[4];                                                               \
    _Pragma("unroll") for (int kfi = 0; kfi < 4; ++kfi) {                      \
      bf16x8 ka = *(const bf16x8*)(lds + (KB) + koA[kfi]);                     \
      bf16x8 kc = *(const bf16x8*)(lds + (KB) + koB[kfi]);                     \
      f32x4 s = mfma16(ka, qa[0], (f32x4){0.f, 0.f, 0.f, 0.f});                \
      sf[kfi] = mfma16(kc, qa[1], s);                                          \
    }                                                                          \
    _Pragma("unroll") for (int kfi = 0; kfi < 4; ++kfi) {                      \
      bf16x4 pk;                                                               \
      _Pragma("unroll") for (int r = 0; r < 4; ++r)                            \
          pk[r] = (bf16)__builtin_exp2f(sf[kfi][r]);                           \
      *(bf16x4*)(myp + pw[kfi]) = pk;                                          \
    }                                                                          \
    _Pragma("unroll") for (int ks = 0; ks < 2; ++ks) {                         \
      bf16x8 pb = *(const bf16x8*)(myp + pr[ks]);                              \
      _Pragma("unroll") for (int df = 0; df < 4; ++df) {                       \
        bf16x8 vv = *(const bf16x8*)(lds + (VB) + vo[ks][df]);                 \
        o[df] = mfma16(vv, pb, o[df]);                                         \
      }                                                                        \
      o[4] = mfma16(vone, pb, o[4]);                                           \
    }                                                                          \
  }

#define VMCNT4 asm volatile("s_waitcnt vmcnt(4)" ::: "memory")
#define VMCNT0 asm volatile("s_waitcnt vmcnt(0)" ::: "memory")
#define BAR __builtin_amdgcn_s_barrier()

  STAGE(0, 16384, 0);
#pragma unroll 1
  for (int kt = 0; kt < 32; kt += 2) {
    STAGE(8192, 24576, kt + 1);  // prefetch stays in flight across barrier
    VMCNT4;                      // wait current buf's 4 loads only
    BAR;
    COMPUTE(0, 16384);
    BAR;
    if (kt + 2 < 32) {
      STAGE(0, 16384, kt + 2);
      VMCNT4;
    } else {
      VMCNT0;
    }
    BAR;
    COMPUTE(8192, 24576);
    BAR;
  }
#undef STAGE
#undef COMPUTE
#undef VMCNT4
#undef VMCNT0
#undef BAR

  // leapfrog: q_new = q + dt*p - (dt^2/2)*gate*pe1
  float dt = dtp[0], gate = gatep[0];
  float c2 = 0.5f * dt * dt * gate;
  float inv = 1.f / o[4][0];  // lr, identical in every lane sharing this q
  int qrow = q0 + fr;
#pragma unroll
  for (int df = 0; df < 4; ++df) {
    int dk = df * 16 + fg * 4;
    bf16x4 qv4 = *(const bf16x4*)(Qrow + (size_t)qrow * nD + dk);
    bf16x4 pv4 = *(const bf16x4*)(Prow + (size_t)qrow * nD + dk);
    bf16x4 ov;
#pragma unroll
    for (int r = 0; r < 4; ++r) {
      float pe = o[df][r] * inv;
      ov[r] = (bf16)((float)qv4[r] + dt * (float)pv4[r] - c2 * pe);
    }
    *(bf16x4*)(qn + ((size_t)(b * nS) + qrow) * nD + h * nDK + dk) = ov;
  }
}

// ---------------- output GEMM: outp = qn @ Wo + bo + x (f32) ----------------
// 64x128 tiles -> grid 384 (was 192 < 256 CUs): all CUs busy, (256,3).
// XCD swizzle: 8 contiguous m-blocks per XCD. LDS: [2 bufs][A 8K | B 16K].
__global__ __launch_bounds__(256, 3) void k_gemm_out(
    const bf16* __restrict__ qn, const bf16* __restrict__ wto,
    const float* __restrict__ bo, const float* __restrict__ x,
    float* __restrict__ outp) {
  __shared__ alignas(16) char smem[49152];
  int t = threadIdx.x, lane = t & 63, w = t >> 6;
  int fr = lane & 15, fg = lane >> 4;
  int wm = w >> 1, wn = w & 1;  // wm: 32-row half, wn: 64-col half
  int p = blockIdx.x;
  int xcd = p & 7, slot = p >> 3;       // slot 0..47
  int by = xcd * 8 + slot / 6;          // 0..63 m-block (contig per XCD)
  int bx = slot % 6;                    // 0..5 n-block
  int m0 = by * 64, n0 = bx * 128;
  const bf16* abase = qn + (size_t)m0 * nD;
  const bf16* bbase = wto + (size_t)n0 * nD;

  f32x4 acc[2][4];
#pragma unroll
  for (int i = 0; i < 2; ++i)
#pragma unroll
    for (int j = 0; j < 4; ++j) acc[i][j] = (f32x4){0.f, 0.f, 0.f, 0.f};

  int aoff[2][2], boff[2][4];
#pragma unroll
  for (int ks = 0; ks < 2; ++ks) {
#pragma unroll
    for (int i = 0; i < 2; ++i) {
      int row = wm * 32 + i * 16 + fr;
      aoff[ks][i] = row * 128 + (((ks * 4 + fg) ^ (row & 7)) << 4);
    }
#pragma unroll
    for (int j = 0; j < 4; ++j) {
      int rowb = wn * 64 + j * 16 + fr;
      boff[ks][j] = 8192 + rowb * 128 + (((ks * 4 + fg) ^ (rowb & 7)) << 4);
    }
  }
  // staging sources: A wave w stages rows [w*16,w*16+16) (2 gll),
  // B rows [w*32,w*32+32) (4 gll); pre-swizzled chunk (involution).
  const bf16 *asrc[2], *bsrc[4];
#pragma unroll
  for (int i = 0; i < 2; ++i) {
    int row = w * 16 + i * 8 + (lane >> 3);
    int c = (lane & 7) ^ (row & 7);
    asrc[i] = abase + (size_t)row * nD + c * 8;
  }
#pragma unroll
  for (int i = 0; i < 4; ++i) {
    int row = w * 32 + i * 8 + (lane >> 3);
    int c = (lane & 7) ^ (row & 7);
    bsrc[i] = bbase + (size_t)row * nD + c * 8;
  }

#define STAGEG(BUF, kt)                                                        \
  {                                                                            \
    _Pragma("unroll") for (int i = 0; i < 2; ++i)                              \
        gll16(asrc[i] + (kt)*64, smem + (BUF) + w * 2048 + i * 1024);          \
    _Pragma("unroll") for (int i = 0; i < 4; ++i)                              \
        gll16(bsrc[i] + (kt)*64, smem + (BUF) + 8192 + w * 4096 + i * 1024);   \
  }

#define COMPUTEG(BUF)                                                          \
  {                                                                            \
    _Pragma("unroll") for (int ks = 0; ks < 2; ++ks) {                         \
      bf16x8 af[2], bfr[4];                                                    \
      _Pragma("unroll") for (int i = 0; i < 2; ++i)                            \
          af[i] = *(const bf16x8*)(smem + (BUF) + aoff[ks][i]);                \
      _Pragma("unroll") for (int j = 0; j < 4; ++j)                            \
          bfr[j] = *(const bf16x8*)(smem + (BUF) + boff[ks][j]);               \
      _Pragma("unroll") for (int i = 0; i < 2; ++i)                            \
          _Pragma("unroll") for (int j = 0; j < 4; ++j) acc[i][j] =            \
          mfma16(af[i], bfr[j], acc[i][j]);                                    \
    }                                                                          \
  }

  STAGEG(0, 0);
  __syncthreads();
#pragma unroll 1
  for (int kt = 0; kt < 12; kt += 2) {
    if (kt + 1 < 12) STAGEG(24576, kt + 1);
    COMPUTEG(0);
    __syncthreads();
    if (kt + 2 < 12) STAGEG(0, kt + 2);
    COMPUTEG(24576);
    __syncthreads();
  }
#undef STAGEG
#undef COMPUTEG

#pragma unroll
  for (int i = 0; i < 2; ++i)
#pragma unroll
    for (int j = 0; j < 4; ++j) {
      int n = n0 + wn * 64 + j * 16 + fr;
      float bias = bo[n];
#pragma unroll
      for (int r = 0; r < 4; ++r) {
        int m = m0 + wm * 32 + i * 16 + fg * 4 + r;
        outp[(size_t)m * nD + n] = acc[i][j][r] + bias + x[(size_t)m * nD + n];
      }
    }
}

// ---------------- LayerNorm (in-place on d_out), one wave per row ----------------
__global__ __launch_bounds__(256) void k_ln(const float* outp,
                                            const float* __restrict__ gamma,
                                            const float* __restrict__ beta,
                                            float* y) {
  int t = threadIdx.x, lane = t & 63, w = t >> 6;
  int row = blockIdx.x * 4 + w;
  const float* rp = outp + (size_t)row * nD;
  float v[12], s1 = 0.f, s2 = 0.f;
#pragma unroll
  for (int i = 0; i < 12; ++i) {
    v[i] = rp[lane + i * 64];
    s1 += v[i];
    s2 += v[i] * v[i];
  }
#pragma unroll
  for (int d = 1; d < 64; d <<= 1) {
    s1 += __shfl_xor(s1, d);
    s2 += __shfl_xor(s2, d);
  }
  float mu = s1 * (1.f / 768.f);
  float var = s2 * (1.f / 768.f) - mu * mu;
  float rstd = rsqrtf(var + LN_EPS);
  float* yp = y + (size_t)row * nD;
#pragma unroll
  for (int i = 0; i < 12; ++i) {
    int n = lane + i * 64;
    yp[n] = (v[i] - mu) * rstd * gamma[n] + beta[n];
  }
}

extern "C" void kernel_launch(void* const* d_in, const int* in_sizes, int n_in,
                              void* d_out, int out_size, void* d_ws, size_t ws_size,
                              hipStream_t stream) {
  const float* x = (const float*)d_in[0];
  const float* Wq = (const float*)d_in[1];
  const float* Wp = (const float*)d_in[2];
  const float* Wk = (const float*)d_in[3];
  const float* Wv = (const float*)d_in[4];
  const float* Wo = (const float*)d_in[5];
  const float* bo = (const float*)d_in[6];
  const float* gamma = (const float*)d_in[7];
  const float* beta = (const float*)d_in[8];
  const float* dt = (const float*)d_in[9];
  const float* gate = (const float*)d_in[10];

  char* ws = (char*)d_ws;
  const size_t szb = (size_t)nM * nD * 2;  // 6,291,456 bytes per bf16 [4096][768]
  bf16* xb = (bf16*)(ws + 0 * szb);        // reused as qn after QPKV GEMM
  bf16* qf = (bf16*)(ws + 1 * szb);
  bf16* pf = (bf16*)(ws + 2 * szb);
  bf16* kf_ = (bf16*)(ws + 3 * szb);
  bf16* vt = (bf16*)(ws + 4 * szb);
  bf16* wt = (bf16*)(ws + 5 * szb);  // 5 * 768*768 bf16 = 5,898,240 bytes
  bf16* qn = xb;
  float* outp = (float*)d_out;  // out-GEMM result, LN runs in place

  k_prep_x<<<dim3(nM * nD / 1024), dim3(256), 0, stream>>>(x, xb);
  k_prep_w<<<dim3(12, 12, 5), dim3(256), 0, stream>>>(Wq, Wp, Wk, Wv, Wo, wt);
  k_gemm_qpkv<<<dim3(768), dim3(256), 0, stream>>>(xb, wt, qf, pf, kf_, vt);
  k_attn<<<dim3(768), dim3(256), 0, stream>>>(qf, pf, kf_, vt, dt, gate, qn);
  k_gemm_out<<<dim3(384), dim3(256), 0, stream>>>(qn, wt + 4 * (size_t)nD * nD, bo, x, outp);
  k_ln<<<dim3(nM / 4), dim3(256), 0, stream>>>(outp, gamma, beta, (float*)d_out);
}

// Round 15
// 109.564 us; speedup vs baseline: 1.5060x; 1.0041x over previous
//
#include <hip/hip_runtime.h>
#include <stdint.h>

typedef __bf16 bf16;
typedef __bf16 bf16x8 __attribute__((ext_vector_type(8)));
typedef __bf16 bf16x4 __attribute__((ext_vector_type(4)));
typedef __bf16 bf16x2 __attribute__((ext_vector_type(2)));
typedef float f32x4 __attribute__((ext_vector_type(4)));

constexpr int nB = 2, nS = 2048, nD = 768, nH = 12, nDK = 64;
constexpr int nM = nB * nS;  // 4096
constexpr float LN_EPS = 1e-5f;

static __device__ __forceinline__ f32x4 mfma16(bf16x8 a, bf16x8 b, f32x4 c) {
  return __builtin_amdgcn_mfma_f32_16x16x32_bf16(a, b, c, 0, 0, 0);
}

static __device__ __forceinline__ void gll16(const void* g, void* l) {
  __builtin_amdgcn_global_load_lds(
      (const __attribute__((address_space(1))) void*)g,
      (__attribute__((address_space(3))) void*)l, 16, 0, 0);
}

// ---------------- prep: x -> bf16 ----------------
__global__ __launch_bounds__(256) void k_prep_x(const float* __restrict__ x,
                                                bf16* __restrict__ xb) {
  int i = (blockIdx.x * 256 + threadIdx.x) * 4;
  float4 v = *(const float4*)(x + i);
  bf16x4 o;
  o[0] = (bf16)v.x; o[1] = (bf16)v.y; o[2] = (bf16)v.z; o[3] = (bf16)v.w;
  *(bf16x4*)(xb + i) = o;
}

// ---------------- prep: weights -> bf16, transposed to [n][k] ----------------
__global__ __launch_bounds__(256) void k_prep_w(
    const float* __restrict__ w0, const float* __restrict__ w1,
    const float* __restrict__ w2, const float* __restrict__ w3,
    const float* __restrict__ w4, bf16* __restrict__ wt) {
  __shared__ float tb[64][65];
  int w = blockIdx.z;
  const float* src = (w == 0) ? w0 : (w == 1) ? w1 : (w == 2) ? w2 : (w == 3) ? w3 : w4;
  int k0 = blockIdx.y * 64, n0 = blockIdx.x * 64;
  int tx = threadIdx.x & 63, ty = threadIdx.x >> 6;
#pragma unroll
  for (int it = 0; it < 16; ++it) {
    int r = it * 4 + ty;
    tb[r][tx] = src[(size_t)(k0 + r) * nD + n0 + tx];
  }
  __syncthreads();
  bf16* dst = wt + (size_t)w * nD * nD;
#pragma unroll
  for (int it = 0; it < 8; ++it) {
    int r2 = it * 8 + ty * 2 + (tx >> 5);
    int k2 = (tx & 31) * 2;
    bf16x2 val;
    val[0] = (bf16)tb[k2][r2];
    val[1] = (bf16)tb[k2 + 1][r2];
    *(bf16x2*)(dst + (size_t)(n0 + r2) * nD + k0 + k2) = val;
  }
}

// ---------------- QPKV GEMM: C = X @ W (Wt is W^T), 128x128 tile, BK=64 ----------------
// SINGLE-buffered m97 structure (stage -> sync -> compute -> sync), 32KB LDS
// -> 3 blocks/CU: entire 768-block grid co-resident (no 1.5-round tail that
// the 64KB dbuf version had). gll staging, hoisted offsets, XCD swizzle.
__global__ __launch_bounds__(256, 3) void k_gemm_qpkv(
    const bf16* __restrict__ xb, const bf16* __restrict__ wt,
    bf16* __restrict__ qf, bf16* __restrict__ pf, bf16* __restrict__ kf_,
    bf16* __restrict__ vt) {
  __shared__ alignas(16) char smem[32768];  // A 16K | B 16K
  int t = threadIdx.x, lane = t & 63, w = t >> 6;
  int fr = lane & 15, fg = lane >> 4;
  int wm = w >> 1, wn = w & 1;
  int p = blockIdx.x;
  int xcd = p & 7, slot = p >> 3;          // slot 0..95
  int combo = (xcd & 3) * 6 + (slot >> 4); // 0..23 = (n-col, widx)
  int yy = (xcd >> 2) * 16 + (slot & 15);  // 0..31 = m-row block
  int xx = combo % 6, widx = combo / 6;
  int m0 = yy * 128, n0 = xx * 128;
  const bf16* abase = xb + (size_t)m0 * nD;
  const bf16* bbase = wt + (size_t)widx * nD * nD + (size_t)n0 * nD;

  f32x4 acc[4][4];
#pragma unroll
  for (int i = 0; i < 4; ++i)
#pragma unroll
    for (int j = 0; j < 4; ++j) acc[i][j] = (f32x4){0.f, 0.f, 0.f, 0.f};

  int aoff[2][4], boff[2][4];
#pragma unroll
  for (int ks = 0; ks < 2; ++ks) {
#pragma unroll
    for (int i = 0; i < 4; ++i) {
      int row = wm * 64 + i * 16 + fr;
      aoff[ks][i] = row * 128 + (((ks * 4 + fg) ^ (row & 7)) << 4);
      int rowb = wn * 64 + i * 16 + fr;
      boff[ks][i] = 16384 + rowb * 128 + (((ks * 4 + fg) ^ (rowb & 7)) << 4);
    }
  }
  const bf16 *asrc[4], *bsrc[4];
#pragma unroll
  for (int i = 0; i < 4; ++i) {
    int row = i * 32 + (t >> 3);
    int c = (t & 7) ^ (row & 7);
    asrc[i] = abase + (size_t)row * nD + c * 8;
    bsrc[i] = bbase + (size_t)row * nD + c * 8;
  }

#pragma unroll 1
  for (int kt = 0; kt < 12; ++kt) {
#pragma unroll
    for (int i = 0; i < 4; ++i) {
      gll16(asrc[i] + kt * 64, smem + i * 4096 + w * 1024);
      gll16(bsrc[i] + kt * 64, smem + 16384 + i * 4096 + w * 1024);
    }
    __syncthreads();
#pragma unroll
    for (int ks = 0; ks < 2; ++ks) {
      bf16x8 af[4], bfr[4];
#pragma unroll
      for (int i = 0; i < 4; ++i)
        af[i] = *(const bf16x8*)(smem + aoff[ks][i]);
#pragma unroll
      for (int j = 0; j < 4; ++j)
        bfr[j] = *(const bf16x8*)(smem + boff[ks][j]);
#pragma unroll
      for (int i = 0; i < 4; ++i)
#pragma unroll
        for (int j = 0; j < 4; ++j) acc[i][j] = mfma16(af[i], bfr[j], acc[i][j]);
    }
    __syncthreads();
  }

  if (widx < 3) {
    bf16* outf = (widx == 0) ? qf : (widx == 1) ? pf : kf_;
    float oscale = (widx == 2) ? 0.18033688f : 1.0f;  // K: DK^-0.5 * log2(e)
#pragma unroll
    for (int i = 0; i < 4; ++i)
#pragma unroll
      for (int j = 0; j < 4; ++j) {
        int n = n0 + wn * 64 + j * 16 + fr;
#pragma unroll
        for (int r = 0; r < 4; ++r) {
          int m = m0 + wm * 64 + i * 16 + fg * 4 + r;
          outf[(size_t)m * nD + n] = (bf16)(acc[i][j][r] * oscale);
        }
      }
  } else {
#pragma unroll
    for (int i = 0; i < 4; ++i)
#pragma unroll
      for (int j = 0; j < 4; ++j) {
        int n = n0 + wn * 64 + j * 16 + fr;
        int h = n >> 6, dk = n & 63;
        int mbase = m0 + wm * 64 + i * 16 + fg * 4;
        int b = mbase >> 11, s = mbase & (nS - 1);
        int bh = b * nH + h;
        bf16x4 pk;
#pragma unroll
        for (int r = 0; r < 4; ++r) pk[r] = (bf16)acc[i][j][r];
        *(bf16x4*)(vt + ((size_t)bh * nDK + dk) * nS + s) = pk;
      }
  }
}

// ---------------- attention pass 1 + leapfrog -> q_new (R13, unchanged) ----------------
__global__ __launch_bounds__(256, 3) void k_attn(
    const bf16* __restrict__ qf, const bf16* __restrict__ pf,
    const bf16* __restrict__ kf_, const bf16* __restrict__ vt,
    const float* __restrict__ dtp, const float* __restrict__ gatep,
    bf16* __restrict__ qn) {
  // LDS: K dbuf @0/@8192 | V dbuf @16384/@24576 | P 4x2KB @32768  = 40KB
  __shared__ alignas(16) char lds[40960];
  int t = threadIdx.x, lane = t & 63, w = t >> 6;
  int fr = lane & 15, fg = lane >> 4;
  int p = blockIdx.x;
  int xcd = p & 7, slot = p >> 3;
  int qt = slot & 31, bh = xcd + 8 * (slot >> 5);
  int b = bh / nH, h = bh % nH;
  int q0 = qt * 64 + w * 16;
  const bf16* Qrow = qf + (size_t)(b * nS) * nD + (size_t)h * nDK;
  const bf16* Prow = pf + (size_t)(b * nS) * nD + (size_t)h * nDK;
  const bf16* Krow = kf_ + (size_t)(b * nS) * nD + (size_t)h * nDK;
  const bf16* Vb = vt + (size_t)bh * nDK * nS;
  char* myp = lds + 32768 + w * 2048;

  bf16x8 qa[2];
#pragma unroll
  for (int ks = 0; ks < 2; ++ks)
    qa[ks] = *(const bf16x8*)(Qrow + (size_t)(q0 + fr) * nD + ks * 32 + fg * 8);

  bf16x8 vone;
#pragma unroll
  for (int i = 0; i < 8; ++i) vone[i] = (bf16)1.0f;

  f32x4 o[5];  // o[0..3]: O^T[dv=df*16+fg*4+r][q=fr]; o[4]: row-sum lr
#pragma unroll
  for (int df = 0; df < 5; ++df) o[df] = (f32x4){0.f, 0.f, 0.f, 0.f};

  int koA[4], koB[4];
#pragma unroll
  for (int kfi = 0; kfi < 4; ++kfi) {
    int key = kfi * 16 + fr;
    koA[kfi] = key * 128 + ((fg ^ (key & 7)) << 4);
    koB[kfi] = key * 128 + (((4 + fg) ^ (key & 7)) << 4);
  }
  int vo[2][4], pr[2], pw[4];
#pragma unroll
  for (int ks = 0; ks < 2; ++ks) {
    pr[ks] = fr * 128 + (((ks * 4 + fg) ^ (fr & 7)) << 4);
#pragma unroll
    for (int df = 0; df < 4; ++df) {
      int row = df * 16 + fr;
      vo[ks][df] = row * 128 + (((ks * 4 + fg) ^ (row & 7)) << 4);
    }
  }
#pragma unroll
  for (int kfi = 0; kfi < 4; ++kfi) {
    int blk16 = kfi * 2 + (fg >> 1);
    pw[kfi] = fr * 128 + (((blk16 ^ (fr & 7)) << 4) | ((fg & 1) << 3));
  }

  const bf16 *ks0, *ks1, *vs0, *vs1;
  {
    int r0 = w * 16 + (lane >> 3), c0 = (lane & 7) ^ (r0 & 7);
    int r1 = r0 + 8, c1 = (lane & 7) ^ (r1 & 7);
    ks0 = Krow + (size_t)r0 * nD + c0 * 8;
    ks1 = Krow + (size_t)r1 * nD + c1 * 8;
    vs0 = Vb + (size_t)r0 * nS + c0 * 8;
    vs1 = Vb + (size_t)r1 * nS + c1 * 8;
  }

#define STAGE(KB, VB, kt)                                                      \
  {                                                                            \
    gll16(ks0 + (size_t)(kt)*64 * nD, lds + (KB) + w * 2048);                  \
    gll16(vs0 + (kt)*64, lds + (VB) + w * 2048);                               \
    gll16(ks1 + (size_t)(kt)*64 * nD, lds + (KB) + w * 2048 + 1024);           \
    gll16(vs1 + (kt)*64, lds + (VB) + w * 2048 + 1024);                        \
  }

#define COMPUTE(KB, VB)                                                        \
  {                                                                            \
    f32x4 sf[4];                                                               \
    _Pragma("unroll") for (int kfi = 0; kfi < 4; ++kfi) {                      \
      bf16x8 ka = *(const bf16x8*)(lds + (KB) + koA[kfi]);                     \
      bf16x8 kc = *(const bf16x8*)(lds + (KB) + koB[kfi]);                     \
      f32x4 s = mfma16(ka, qa[0], (f32x4){0.f, 0.f, 0.f, 0.f});                \
      sf[kfi] = mfma16(kc, qa[1], s);                                          \
    }                                                                          \
    _Pragma("unroll") for (int kfi = 0; kfi < 4; ++kfi) {                      \
      bf16x4 pk;                                                               \
      _Pragma("unroll") for (int r = 0; r < 4; ++r)                            \
          pk[r] = (bf16)__builtin_exp2f(sf[kfi][r]);                           \
      *(bf16x4*)(myp + pw[kfi]) = pk;                                          \
    }                                                                          \
    _Pragma("unroll") for (int ks = 0; ks < 2; ++ks) {                         \
      bf16x8 pb = *(const bf16x8*)(myp + pr[ks]);                              \
      _Pragma("unroll") for (int df = 0; df < 4; ++df) {                       \
        bf16x8 vv = *(const bf16x8*)(lds + (VB) + vo[ks][df]);                 \
        o[df] = mfma16(vv, pb, o[df]);                                         \
      }                                                                        \
      o[4] = mfma16(vone, pb, o[4]);                                           \
    }                                                                          \
  }

#define VMCNT4 asm volatile("s_waitcnt vmcnt(4)" ::: "memory")
#define VMCNT0 asm volatile("s_waitcnt vmcnt(0)" ::: "memory")
#define BAR __builtin_amdgcn_s_barrier()

  STAGE(0, 16384, 0);
#pragma unroll 1
  for (int kt = 0; kt < 32; kt += 2) {
    STAGE(8192, 24576, kt + 1);  // prefetch stays in flight across barrier
    VMCNT4;                      // wait current buf's 4 loads only
    BAR;
    COMPUTE(0, 16384);
    BAR;
    if (kt + 2 < 32) {
      STAGE(0, 16384, kt + 2);
      VMCNT4;
    } else {
      VMCNT0;
    }
    BAR;
    COMPUTE(8192, 24576);
    BAR;
  }
#undef STAGE
#undef COMPUTE
#undef VMCNT4
#undef VMCNT0
#undef BAR

  // leapfrog: q_new = q + dt*p - (dt^2/2)*gate*pe1
  float dt = dtp[0], gate = gatep[0];
  float c2 = 0.5f * dt * dt * gate;
  float inv = 1.f / o[4][0];  // lr, identical in every lane sharing this q
  int qrow = q0 + fr;
#pragma unroll
  for (int df = 0; df < 4; ++df) {
    int dk = df * 16 + fg * 4;
    bf16x4 qv4 = *(const bf16x4*)(Qrow + (size_t)qrow * nD + dk);
    bf16x4 pv4 = *(const bf16x4*)(Prow + (size_t)qrow * nD + dk);
    bf16x4 ov;
#pragma unroll
    for (int r = 0; r < 4; ++r) {
      float pe = o[df][r] * inv;
      ov[r] = (bf16)((float)qv4[r] + dt * (float)pv4[r] - c2 * pe);
    }
    *(bf16x4*)(qn + ((size_t)(b * nS) + qrow) * nD + h * nDK + dk) = ov;
  }
}

// ---------------- output GEMM: outp = qn @ Wo + bo + x (f32) ----------------
// 64x128 tiles, grid 384, SINGLE-buffered 24KB (A 8K | B 16K), (256,3).
__global__ __launch_bounds__(256, 3) void k_gemm_out(
    const bf16* __restrict__ qn, const bf16* __restrict__ wto,
    const float* __restrict__ bo, const float* __restrict__ x,
    float* __restrict__ outp) {
  __shared__ alignas(16) char smem[24576];
  int t = threadIdx.x, lane = t & 63, w = t >> 6;
  int fr = lane & 15, fg = lane >> 4;
  int wm = w >> 1, wn = w & 1;  // wm: 32-row half, wn: 64-col half
  int p = blockIdx.x;
  int xcd = p & 7, slot = p >> 3;       // slot 0..47
  int by = xcd * 8 + slot / 6;          // 0..63 m-block (contig per XCD)
  int bx = slot % 6;                    // 0..5 n-block
  int m0 = by * 64, n0 = bx * 128;
  const bf16* abase = qn + (size_t)m0 * nD;
  const bf16* bbase = wto + (size_t)n0 * nD;

  f32x4 acc[2][4];
#pragma unroll
  for (int i = 0; i < 2; ++i)
#pragma unroll
    for (int j = 0; j < 4; ++j) acc[i][j] = (f32x4){0.f, 0.f, 0.f, 0.f};

  int aoff[2][2], boff[2][4];
#pragma unroll
  for (int ks = 0; ks < 2; ++ks) {
#pragma unroll
    for (int i = 0; i < 2; ++i) {
      int row = wm * 32 + i * 16 + fr;
      aoff[ks][i] = row * 128 + (((ks * 4 + fg) ^ (row & 7)) << 4);
    }
#pragma unroll
    for (int j = 0; j < 4; ++j) {
      int rowb = wn * 64 + j * 16 + fr;
      boff[ks][j] = 8192 + rowb * 128 + (((ks * 4 + fg) ^ (rowb & 7)) << 4);
    }
  }
  const bf16 *asrc[2], *bsrc[4];
#pragma unroll
  for (int i = 0; i < 2; ++i) {
    int row = w * 16 + i * 8 + (lane >> 3);
    int c = (lane & 7) ^ (row & 7);
    asrc[i] = abase + (size_t)row * nD + c * 8;
  }
#pragma unroll
  for (int i = 0; i < 4; ++i) {
    int row = w * 32 + i * 8 + (lane >> 3);
    int c = (lane & 7) ^ (row & 7);
    bsrc[i] = bbase + (size_t)row * nD + c * 8;
  }

#pragma unroll 1
  for (int kt = 0; kt < 12; ++kt) {
#pragma unroll
    for (int i = 0; i < 2; ++i)
      gll16(asrc[i] + kt * 64, smem + w * 2048 + i * 1024);
#pragma unroll
    for (int i = 0; i < 4; ++i)
      gll16(bsrc[i] + kt * 64, smem + 8192 + w * 4096 + i * 1024);
    __syncthreads();
#pragma unroll
    for (int ks = 0; ks < 2; ++ks) {
      bf16x8 af[2], bfr[4];
#pragma unroll
      for (int i = 0; i < 2; ++i)
        af[i] = *(const bf16x8*)(smem + aoff[ks][i]);
#pragma unroll
      for (int j = 0; j < 4; ++j)
        bfr[j] = *(const bf16x8*)(smem + boff[ks][j]);
#pragma unroll
      for (int i = 0; i < 2; ++i)
#pragma unroll
        for (int j = 0; j < 4; ++j) acc[i][j] = mfma16(af[i], bfr[j], acc[i][j]);
    }
    __syncthreads();
  }

#pragma unroll
  for (int i = 0; i < 2; ++i)
#pragma unroll
    for (int j = 0; j < 4; ++j) {
      int n = n0 + wn * 64 + j * 16 + fr;
      float bias = bo[n];
#pragma unroll
      for (int r = 0; r < 4; ++r) {
        int m = m0 + wm * 32 + i * 16 + fg * 4 + r;
        outp[(size_t)m * nD + n] = acc[i][j][r] + bias + x[(size_t)m * nD + n];
      }
    }
}

// ---------------- LayerNorm (in-place on d_out), one wave per row ----------------
__global__ __launch_bounds__(256) void k_ln(const float* outp,
                                            const float* __restrict__ gamma,
                                            const float* __restrict__ beta,
                                            float* y) {
  int t = threadIdx.x, lane = t & 63, w = t >> 6;
  int row = blockIdx.x * 4 + w;
  const float* rp = outp + (size_t)row * nD;
  float v[12], s1 = 0.f, s2 = 0.f;
#pragma unroll
  for (int i = 0; i < 12; ++i) {
    v[i] = rp[lane + i * 64];
    s1 += v[i];
    s2 += v[i] * v[i];
  }
#pragma unroll
  for (int d = 1; d < 64; d <<= 1) {
    s1 += __shfl_xor(s1, d);
    s2 += __shfl_xor(s2, d);
  }
  float mu = s1 * (1.f / 768.f);
  float var = s2 * (1.f / 768.f) - mu * mu;
  float rstd = rsqrtf(var + LN_EPS);
  float* yp = y + (size_t)row * nD;
#pragma unroll
  for (int i = 0; i < 12; ++i) {
    int n = lane + i * 64;
    yp[n] = (v[i] - mu) * rstd * gamma[n] + beta[n];
  }
}

extern "C" void kernel_launch(void* const* d_in, const int* in_sizes, int n_in,
                              void* d_out, int out_size, void* d_ws, size_t ws_size,
                              hipStream_t stream) {
  const float* x = (const float*)d_in[0];
  const float* Wq = (const float*)d_in[1];
  const float* Wp = (const float*)d_in[2];
  const float* Wk = (const float*)d_in[3];
  const float* Wv = (const float*)d_in[4];
  const float* Wo = (const float*)d_in[5];
  const float* bo = (const float*)d_in[6];
  const float* gamma = (const float*)d_in[7];
  const float* beta = (const float*)d_in[8];
  const float* dt = (const float*)d_in[9];
  const float* gate = (const float*)d_in[10];

  char* ws = (char*)d_ws;
  const size_t szb = (size_t)nM * nD * 2;  // 6,291,456 bytes per bf16 [4096][768]
  bf16* xb = (bf16*)(ws + 0 * szb);        // reused as qn after QPKV GEMM
  bf16* qf = (bf16*)(ws + 1 * szb);
  bf16* pf = (bf16*)(ws + 2 * szb);
  bf16* kf_ = (bf16*)(ws + 3 * szb);
  bf16* vt = (bf16*)(ws + 4 * szb);
  bf16* wt = (bf16*)(ws + 5 * szb);  // 5 * 768*768 bf16 = 5,898,240 bytes
  bf16* qn = xb;
  float* outp = (float*)d_out;  // out-GEMM result, LN runs in place

  k_prep_x<<<dim3(nM * nD / 1024), dim3(256), 0, stream>>>(x, xb);
  k_prep_w<<<dim3(12, 12, 5), dim3(256), 0, stream>>>(Wq, Wp, Wk, Wv, Wo, wt);
  k_gemm_qpkv<<<dim3(768), dim3(256), 0, stream>>>(xb, wt, qf, pf, kf_, vt);
  k_attn<<<dim3(768), dim3(256), 0, stream>>>(qf, pf, kf_, vt, dt, gate, qn);
  k_gemm_out<<<dim3(384), dim3(256), 0, stream>>>(qn, wt + 4 * (size_t)nD * nD, bo, x, outp);
  k_ln<<<dim3(nM / 4), dim3(256), 0, stream>>>(outp, gamma, beta, (float*)d_out);
}

// Round 16
// 107.581 us; speedup vs baseline: 1.5338x; 1.0184x over previous
//
#include <hip/hip_runtime.h>
#include <stdint.h>

typedef __bf16 bf16;
typedef __bf16 bf16x8 __attribute__((ext_vector_type(8)));
typedef __bf16 bf16x4 __attribute__((ext_vector_type(4)));
typedef __bf16 bf16x2 __attribute__((ext_vector_type(2)));
typedef float f32x4 __attribute__((ext_vector_type(4)));

constexpr int nB = 2, nS = 2048, nD = 768, nH = 12, nDK = 64;
constexpr int nM = nB * nS;  // 4096
constexpr float LN_EPS = 1e-5f;

static __device__ __forceinline__ f32x4 mfma16(bf16x8 a, bf16x8 b, f32x4 c) {
  return __builtin_amdgcn_mfma_f32_16x16x32_bf16(a, b, c, 0, 0, 0);
}

static __device__ __forceinline__ void gll16(const void* g, void* l) {
  __builtin_amdgcn_global_load_lds(
      (const __attribute__((address_space(1))) void*)g,
      (__attribute__((address_space(3))) void*)l, 16, 0, 0);
}

// ---------------- merged prep: x -> bf16 (blocks 0..3071) and
// weights -> bf16 transposed [n][k] (blocks 3072..3791) ----------------
__global__ __launch_bounds__(256) void k_prep(
    const float* __restrict__ x, bf16* __restrict__ xb,
    const float* __restrict__ w0, const float* __restrict__ w1,
    const float* __restrict__ w2, const float* __restrict__ w3,
    const float* __restrict__ w4, bf16* __restrict__ wt) {
  __shared__ float tb[64][65];
  int bid = blockIdx.x;
  if (bid < 3072) {
    int i = (bid * 256 + threadIdx.x) * 4;
    float4 v = *(const float4*)(x + i);
    bf16x4 o;
    o[0] = (bf16)v.x; o[1] = (bf16)v.y; o[2] = (bf16)v.z; o[3] = (bf16)v.w;
    *(bf16x4*)(xb + i) = o;
    return;
  }
  int id = bid - 3072;
  int w = id / 144, rem = id % 144;
  int k0 = (rem / 12) * 64, n0 = (rem % 12) * 64;
  const float* src = (w == 0) ? w0 : (w == 1) ? w1 : (w == 2) ? w2 : (w == 3) ? w3 : w4;
  int tx = threadIdx.x & 63, ty = threadIdx.x >> 6;
#pragma unroll
  for (int it = 0; it < 16; ++it) {
    int r = it * 4 + ty;
    tb[r][tx] = src[(size_t)(k0 + r) * nD + n0 + tx];
  }
  __syncthreads();
  bf16* dst = wt + (size_t)w * nD * nD;
#pragma unroll
  for (int it = 0; it < 8; ++it) {
    int r2 = it * 8 + ty * 2 + (tx >> 5);
    int k2 = (tx & 31) * 2;
    bf16x2 val;
    val[0] = (bf16)tb[k2][r2];
    val[1] = (bf16)tb[k2 + 1][r2];
    *(bf16x2*)(dst + (size_t)(n0 + r2) * nD + k0 + k2) = val;
  }
}

// ---------------- QPKV GEMM: C = X @ W (Wt is W^T), 128x128 tile, BK=64 ----------------
// Single-buffered m97 structure, 32KB LDS, 3 blocks/CU, XCD swizzle (R15).
__global__ __launch_bounds__(256, 3) void k_gemm_qpkv(
    const bf16* __restrict__ xb, const bf16* __restrict__ wt,
    bf16* __restrict__ qf, bf16* __restrict__ pf, bf16* __restrict__ kf_,
    bf16* __restrict__ vt) {
  __shared__ alignas(16) char smem[32768];  // A 16K | B 16K
  int t = threadIdx.x, lane = t & 63, w = t >> 6;
  int fr = lane & 15, fg = lane >> 4;
  int wm = w >> 1, wn = w & 1;
  int p = blockIdx.x;
  int xcd = p & 7, slot = p >> 3;          // slot 0..95
  int combo = (xcd & 3) * 6 + (slot >> 4); // 0..23 = (n-col, widx)
  int yy = (xcd >> 2) * 16 + (slot & 15);  // 0..31 = m-row block
  int xx = combo % 6, widx = combo / 6;
  int m0 = yy * 128, n0 = xx * 128;
  const bf16* abase = xb + (size_t)m0 * nD;
  const bf16* bbase = wt + (size_t)widx * nD * nD + (size_t)n0 * nD;

  f32x4 acc[4][4];
#pragma unroll
  for (int i = 0; i < 4; ++i)
#pragma unroll
    for (int j = 0; j < 4; ++j) acc[i][j] = (f32x4){0.f, 0.f, 0.f, 0.f};

  int aoff[2][4], boff[2][4];
#pragma unroll
  for (int ks = 0; ks < 2; ++ks) {
#pragma unroll
    for (int i = 0; i < 4; ++i) {
      int row = wm * 64 + i * 16 + fr;
      aoff[ks][i] = row * 128 + (((ks * 4 + fg) ^ (row & 7)) << 4);
      int rowb = wn * 64 + i * 16 + fr;
      boff[ks][i] = 16384 + rowb * 128 + (((ks * 4 + fg) ^ (rowb & 7)) << 4);
    }
  }
  const bf16 *asrc[4], *bsrc[4];
#pragma unroll
  for (int i = 0; i < 4; ++i) {
    int row = i * 32 + (t >> 3);
    int c = (t & 7) ^ (row & 7);
    asrc[i] = abase + (size_t)row * nD + c * 8;
    bsrc[i] = bbase + (size_t)row * nD + c * 8;
  }

#pragma unroll 1
  for (int kt = 0; kt < 12; ++kt) {
#pragma unroll
    for (int i = 0; i < 4; ++i) {
      gll16(asrc[i] + kt * 64, smem + i * 4096 + w * 1024);
      gll16(bsrc[i] + kt * 64, smem + 16384 + i * 4096 + w * 1024);
    }
    __syncthreads();
#pragma unroll
    for (int ks = 0; ks < 2; ++ks) {
      bf16x8 af[4], bfr[4];
#pragma unroll
      for (int i = 0; i < 4; ++i)
        af[i] = *(const bf16x8*)(smem + aoff[ks][i]);
#pragma unroll
      for (int j = 0; j < 4; ++j)
        bfr[j] = *(const bf16x8*)(smem + boff[ks][j]);
#pragma unroll
      for (int i = 0; i < 4; ++i)
#pragma unroll
        for (int j = 0; j < 4; ++j) acc[i][j] = mfma16(af[i], bfr[j], acc[i][j]);
    }
    __syncthreads();
  }

  if (widx < 3) {
    bf16* outf = (widx == 0) ? qf : (widx == 1) ? pf : kf_;
    float oscale = (widx == 2) ? 0.18033688f : 1.0f;  // K: DK^-0.5 * log2(e)
#pragma unroll
    for (int i = 0; i < 4; ++i)
#pragma unroll
      for (int j = 0; j < 4; ++j) {
        int n = n0 + wn * 64 + j * 16 + fr;
#pragma unroll
        for (int r = 0; r < 4; ++r) {
          int m = m0 + wm * 64 + i * 16 + fg * 4 + r;
          outf[(size_t)m * nD + n] = (bf16)(acc[i][j][r] * oscale);
        }
      }
  } else {
#pragma unroll
    for (int i = 0; i < 4; ++i)
#pragma unroll
      for (int j = 0; j < 4; ++j) {
        int n = n0 + wn * 64 + j * 16 + fr;
        int h = n >> 6, dk = n & 63;
        int mbase = m0 + wm * 64 + i * 16 + fg * 4;
        int b = mbase >> 11, s = mbase & (nS - 1);
        int bh = b * nH + h;
        bf16x4 pk;
#pragma unroll
        for (int r = 0; r < 4; ++r) pk[r] = (bf16)acc[i][j][r];
        *(bf16x4*)(vt + ((size_t)bh * nDK + dk) * nS + s) = pk;
      }
  }
}

// ---------------- attention pass 1 + leapfrog -> q_new (R13, unchanged) ----------------
__global__ __launch_bounds__(256, 3) void k_attn(
    const bf16* __restrict__ qf, const bf16* __restrict__ pf,
    const bf16* __restrict__ kf_, const bf16* __restrict__ vt,
    const float* __restrict__ dtp, const float* __restrict__ gatep,
    bf16* __restrict__ qn) {
  // LDS: K dbuf @0/@8192 | V dbuf @16384/@24576 | P 4x2KB @32768  = 40KB
  __shared__ alignas(16) char lds[40960];
  int t = threadIdx.x, lane = t & 63, w = t >> 6;
  int fr = lane & 15, fg = lane >> 4;
  int p = blockIdx.x;
  int xcd = p & 7, slot = p >> 3;
  int qt = slot & 31, bh = xcd + 8 * (slot >> 5);
  int b = bh / nH, h = bh % nH;
  int q0 = qt * 64 + w * 16;
  const bf16* Qrow = qf + (size_t)(b * nS) * nD + (size_t)h * nDK;
  const bf16* Prow = pf + (size_t)(b * nS) * nD + (size_t)h * nDK;
  const bf16* Krow = kf_ + (size_t)(b * nS) * nD + (size_t)h * nDK;
  const bf16* Vb = vt + (size_t)bh * nDK * nS;
  char* myp = lds + 32768 + w * 2048;

  bf16x8 qa[2];
#pragma unroll
  for (int ks = 0; ks < 2; ++ks)
    qa[ks] = *(const bf16x8*)(Qrow + (size_t)(q0 + fr) * nD + ks * 32 + fg * 8);

  bf16x8 vone;
#pragma unroll
  for (int i = 0; i < 8; ++i) vone[i] = (bf16)1.0f;

  f32x4 o[5];  // o[0..3]: O^T[dv=df*16+fg*4+r][q=fr]; o[4]: row-sum lr
#pragma unroll
  for (int df = 0; df < 5; ++df) o[df] = (f32x4){0.f, 0.f, 0.f, 0.f};

  int koA[4], koB[4];
#pragma unroll
  for (int kfi = 0; kfi < 4; ++kfi) {
    int key = kfi * 16 + fr;
    koA[kfi] = key * 128 + ((fg ^ (key & 7)) << 4);
    koB[kfi] = key * 128 + (((4 + fg) ^ (key & 7)) << 4);
  }
  int vo[2][4], pr[2], pw[4];
#pragma unroll
  for (int ks = 0; ks < 2; ++ks) {
    pr[ks] = fr * 128 + (((ks * 4 + fg) ^ (fr & 7)) << 4);
#pragma unroll
    for (int df = 0; df < 4; ++df) {
      int row = df * 16 + fr;
      vo[ks][df] = row * 128 + (((ks * 4 + fg) ^ (row & 7)) << 4);
    }
  }
#pragma unroll
  for (int kfi = 0; kfi < 4; ++kfi) {
    int blk16 = kfi * 2 + (fg >> 1);
    pw[kfi] = fr * 128 + (((blk16 ^ (fr & 7)) << 4) | ((fg & 1) << 3));
  }

  const bf16 *ks0, *ks1, *vs0, *vs1;
  {
    int r0 = w * 16 + (lane >> 3), c0 = (lane & 7) ^ (r0 & 7);
    int r1 = r0 + 8, c1 = (lane & 7) ^ (r1 & 7);
    ks0 = Krow + (size_t)r0 * nD + c0 * 8;
    ks1 = Krow + (size_t)r1 * nD + c1 * 8;
    vs0 = Vb + (size_t)r0 * nS + c0 * 8;
    vs1 = Vb + (size_t)r1 * nS + c1 * 8;
  }

#define STAGE(KB, VB, kt)                                                      \
  {                                                                            \
    gll16(ks0 + (size_t)(kt)*64 * nD, lds + (KB) + w * 2048);                  \
    gll16(vs0 + (kt)*64, lds + (VB) + w * 2048);                               \
    gll16(ks1 + (size_t)(kt)*64 * nD, lds + (KB) + w * 2048 + 1024);           \
    gll16(vs1 + (kt)*64, lds + (VB) + w * 2048 + 1024);                        \
  }

#define COMPUTE(KB, VB)                                                        \
  {                                                                            \
    f32x4 sf[4];                                                               \
    _Pragma("unroll") for (int kfi = 0; kfi < 4; ++kfi) {                      \
      bf16x8 ka = *(const bf16x8*)(lds + (KB) + koA[kfi]);                     \
      bf16x8 kc = *(const bf16x8*)(lds + (KB) + koB[kfi]);                     \
      f32x4 s = mfma16(ka, qa[0], (f32x4){0.f, 0.f, 0.f, 0.f});                \
      sf[kfi] = mfma16(kc, qa[1], s);                                          \
    }                                                                          \
    _Pragma("unroll") for (int kfi = 0; kfi < 4; ++kfi) {                      \
      bf16x4 pk;                                                               \
      _Pragma("unroll") for (int r = 0; r < 4; ++r)                            \
          pk[r] = (bf16)__builtin_exp2f(sf[kfi][r]);                           \
      *(bf16x4*)(myp + pw[kfi]) = pk;                                          \
    }                                                                          \
    _Pragma("unroll") for (int ks = 0; ks < 2; ++ks) {                         \
      bf16x8 pb = *(const bf16x8*)(myp + pr[ks]);                              \
      _Pragma("unroll") for (int df = 0; df < 4; ++df) {                       \
        bf16x8 vv = *(const bf16x8*)(lds + (VB) + vo[ks][df]);                 \
        o[df] = mfma16(vv, pb, o[df]);                                         \
      }                                                                        \
      o[4] = mfma16(vone, pb, o[4]);                                           \
    }                                                                          \
  }

#define VMCNT4 asm volatile("s_waitcnt vmcnt(4)" ::: "memory")
#define VMCNT0 asm volatile("s_waitcnt vmcnt(0)" ::: "memory")
#define BAR __builtin_amdgcn_s_barrier()

  STAGE(0, 16384, 0);
#pragma unroll 1
  for (int kt = 0; kt < 32; kt += 2) {
    STAGE(8192, 24576, kt + 1);  // prefetch stays in flight across barrier
    VMCNT4;                      // wait current buf's 4 loads only
    BAR;
    COMPUTE(0, 16384);
    BAR;
    if (kt + 2 < 32) {
      STAGE(0, 16384, kt + 2);
      VMCNT4;
    } else {
      VMCNT0;
    }
    BAR;
    COMPUTE(8192, 24576);
    BAR;
  }
#undef STAGE
#undef COMPUTE
#undef VMCNT4
#undef VMCNT0
#undef BAR

  // leapfrog: q_new = q + dt*p - (dt^2/2)*gate*pe1
  float dt = dtp[0], gate = gatep[0];
  float c2 = 0.5f * dt * dt * gate;
  float inv = 1.f / o[4][0];  // lr, identical in every lane sharing this q
  int qrow = q0 + fr;
#pragma unroll
  for (int df = 0; df < 4; ++df) {
    int dk = df * 16 + fg * 4;
    bf16x4 qv4 = *(const bf16x4*)(Qrow + (size_t)qrow * nD + dk);
    bf16x4 pv4 = *(const bf16x4*)(Prow + (size_t)qrow * nD + dk);
    bf16x4 ov;
#pragma unroll
    for (int r = 0; r < 4; ++r) {
      float pe = o[df][r] * inv;
      ov[r] = (bf16)((float)qv4[r] + dt * (float)pv4[r] - c2 * pe);
    }
    *(bf16x4*)(qn + ((size_t)(b * nS) + qrow) * nD + h * nDK + dk) = ov;
  }
}

// ---------------- output GEMM: gw = bf16(qn @ Wo)  (bias+residual moved to LN) ----------------
// 64x128 tiles, grid 384, single-buffered 24KB, (256,3), XCD swizzle (R15).
__global__ __launch_bounds__(256, 3) void k_gemm_out(
    const bf16* __restrict__ qn, const bf16* __restrict__ wto,
    bf16* __restrict__ gw) {
  __shared__ alignas(16) char smem[24576];
  int t = threadIdx.x, lane = t & 63, w = t >> 6;
  int fr = lane & 15, fg = lane >> 4;
  int wm = w >> 1, wn = w & 1;  // wm: 32-row half, wn: 64-col half
  int p = blockIdx.x;
  int xcd = p & 7, slot = p >> 3;       // slot 0..47
  int by = xcd * 8 + slot / 6;          // 0..63 m-block (contig per XCD)
  int bx = slot % 6;                    // 0..5 n-block
  int m0 = by * 64, n0 = bx * 128;
  const bf16* abase = qn + (size_t)m0 * nD;
  const bf16* bbase = wto + (size_t)n0 * nD;

  f32x4 acc[2][4];
#pragma unroll
  for (int i = 0; i < 2; ++i)
#pragma unroll
    for (int j = 0; j < 4; ++j) acc[i][j] = (f32x4){0.f, 0.f, 0.f, 0.f};

  int aoff[2][2], boff[2][4];
#pragma unroll
  for (int ks = 0; ks < 2; ++ks) {
#pragma unroll
    for (int i = 0; i < 2; ++i) {
      int row = wm * 32 + i * 16 + fr;
      aoff[ks][i] = row * 128 + (((ks * 4 + fg) ^ (row & 7)) << 4);
    }
#pragma unroll
    for (int j = 0; j < 4; ++j) {
      int rowb = wn * 64 + j * 16 + fr;
      boff[ks][j] = 8192 + rowb * 128 + (((ks * 4 + fg) ^ (rowb & 7)) << 4);
    }
  }
  const bf16 *asrc[2], *bsrc[4];
#pragma unroll
  for (int i = 0; i < 2; ++i) {
    int row = w * 16 + i * 8 + (lane >> 3);
    int c = (lane & 7) ^ (row & 7);
    asrc[i] = abase + (size_t)row * nD + c * 8;
  }
#pragma unroll
  for (int i = 0; i < 4; ++i) {
    int row = w * 32 + i * 8 + (lane >> 3);
    int c = (lane & 7) ^ (row & 7);
    bsrc[i] = bbase + (size_t)row * nD + c * 8;
  }

#pragma unroll 1
  for (int kt = 0; kt < 12; ++kt) {
#pragma unroll
    for (int i = 0; i < 2; ++i)
      gll16(asrc[i] + kt * 64, smem + w * 2048 + i * 1024);
#pragma unroll
    for (int i = 0; i < 4; ++i)
      gll16(bsrc[i] + kt * 64, smem + 8192 + w * 4096 + i * 1024);
    __syncthreads();
#pragma unroll
    for (int ks = 0; ks < 2; ++ks) {
      bf16x8 af[2], bfr[4];
#pragma unroll
      for (int i = 0; i < 2; ++i)
        af[i] = *(const bf16x8*)(smem + aoff[ks][i]);
#pragma unroll
      for (int j = 0; j < 4; ++j)
        bfr[j] = *(const bf16x8*)(smem + boff[ks][j]);
#pragma unroll
      for (int i = 0; i < 2; ++i)
#pragma unroll
        for (int j = 0; j < 4; ++j) acc[i][j] = mfma16(af[i], bfr[j], acc[i][j]);
    }
    __syncthreads();
  }

#pragma unroll
  for (int i = 0; i < 2; ++i)
#pragma unroll
    for (int j = 0; j < 4; ++j) {
      int n = n0 + wn * 64 + j * 16 + fr;
#pragma unroll
      for (int r = 0; r < 4; ++r) {
        int m = m0 + wm * 32 + i * 16 + fg * 4 + r;
        gw[(size_t)m * nD + n] = (bf16)acc[i][j][r];
      }
    }
}

// ---------------- LayerNorm: y = LN(gw + bo + x) * gamma + beta ----------------
// One wave per row; bf16x2 / float2 vectorized loads (G13).
__global__ __launch_bounds__(256) void k_ln(const bf16* __restrict__ gw,
                                            const float* __restrict__ bo,
                                            const float* __restrict__ x,
                                            const float* __restrict__ gamma,
                                            const float* __restrict__ beta,
                                            float* __restrict__ y) {
  int t = threadIdx.x, lane = t & 63, w = t >> 6;
  int row = blockIdx.x * 4 + w;
  const bf16* gp = gw + (size_t)row * nD;
  const float* xp = x + (size_t)row * nD;
  float2 v[6];
  float s1 = 0.f, s2 = 0.f;
#pragma unroll
  for (int i = 0; i < 6; ++i) {
    int col = i * 128 + lane * 2;
    bf16x2 g2 = *(const bf16x2*)(gp + col);
    float2 x2 = *(const float2*)(xp + col);
    float2 b2 = *(const float2*)(bo + col);
    float v0 = (float)g2[0] + x2.x + b2.x;
    float v1 = (float)g2[1] + x2.y + b2.y;
    v[i].x = v0;
    v[i].y = v1;
    s1 += v0 + v1;
    s2 += v0 * v0 + v1 * v1;
  }
#pragma unroll
  for (int d = 1; d < 64; d <<= 1) {
    s1 += __shfl_xor(s1, d);
    s2 += __shfl_xor(s2, d);
  }
  float mu = s1 * (1.f / 768.f);
  float var = s2 * (1.f / 768.f) - mu * mu;
  float rstd = rsqrtf(var + LN_EPS);
  float* yp = y + (size_t)row * nD;
#pragma unroll
  for (int i = 0; i < 6; ++i) {
    int col = i * 128 + lane * 2;
    float2 g2 = *(const float2*)(gamma + col);
    float2 be = *(const float2*)(beta + col);
    float2 o;
    o.x = (v[i].x - mu) * rstd * g2.x + be.x;
    o.y = (v[i].y - mu) * rstd * g2.y + be.y;
    *(float2*)(yp + col) = o;
  }
}

extern "C" void kernel_launch(void* const* d_in, const int* in_sizes, int n_in,
                              void* d_out, int out_size, void* d_ws, size_t ws_size,
                              hipStream_t stream) {
  const float* x = (const float*)d_in[0];
  const float* Wq = (const float*)d_in[1];
  const float* Wp = (const float*)d_in[2];
  const float* Wk = (const float*)d_in[3];
  const float* Wv = (const float*)d_in[4];
  const float* Wo = (const float*)d_in[5];
  const float* bo = (const float*)d_in[6];
  const float* gamma = (const float*)d_in[7];
  const float* beta = (const float*)d_in[8];
  const float* dt = (const float*)d_in[9];
  const float* gate = (const float*)d_in[10];

  char* ws = (char*)d_ws;
  const size_t szb = (size_t)nM * nD * 2;  // 6,291,456 bytes per bf16 [4096][768]
  bf16* xb = (bf16*)(ws + 0 * szb);        // reused as qn after QPKV GEMM
  bf16* qf = (bf16*)(ws + 1 * szb);        // reused as gw after attn
  bf16* pf = (bf16*)(ws + 2 * szb);
  bf16* kf_ = (bf16*)(ws + 3 * szb);
  bf16* vt = (bf16*)(ws + 4 * szb);
  bf16* wt = (bf16*)(ws + 5 * szb);  // 5 * 768*768 bf16 = 5,898,240 bytes
  bf16* qn = xb;
  bf16* gw = qf;  // qf dead after attn

  k_prep<<<dim3(3792), dim3(256), 0, stream>>>(x, xb, Wq, Wp, Wk, Wv, Wo, wt);
  k_gemm_qpkv<<<dim3(768), dim3(256), 0, stream>>>(xb, wt, qf, pf, kf_, vt);
  k_attn<<<dim3(768), dim3(256), 0, stream>>>(qf, pf, kf_, vt, dt, gate, qn);
  k_gemm_out<<<dim3(384), dim3(256), 0, stream>>>(qn, wt + 4 * (size_t)nD * nD, gw);
  k_ln<<<dim3(nM / 4), dim3(256), 0, stream>>>(gw, bo, x, gamma, beta, (float*)d_out);
}

// Round 18
// 107.327 us; speedup vs baseline: 1.5374x; 1.0024x over previous
//
#include <hip/hip_runtime.h>
#include <stdint.h>

typedef __bf16 bf16;
typedef __bf16 bf16x8 __attribute__((ext_vector_type(8)));
typedef __bf16 bf16x4 __attribute__((ext_vector_type(4)));
typedef __bf16 bf16x2 __attribute__((ext_vector_type(2)));
typedef float f32x4 __attribute__((ext_vector_type(4)));

constexpr int nB = 2, nS = 2048, nD = 768, nH = 12, nDK = 64;
constexpr int nM = nB * nS;  // 4096
constexpr float LN_EPS = 1e-5f;

static __device__ __forceinline__ f32x4 mfma16(bf16x8 a, bf16x8 b, f32x4 c) {
  return __builtin_amdgcn_mfma_f32_16x16x32_bf16(a, b, c, 0, 0, 0);
}

static __device__ __forceinline__ void gll16(const void* g, void* l) {
  __builtin_amdgcn_global_load_lds(
      (const __attribute__((address_space(1))) void*)g,
      (__attribute__((address_space(3))) void*)l, 16, 0, 0);
}

// Opaque register pin: compiler cannot rematerialize what it can't see
// through, so the value MUST stay resident in a VGPR across the loop.
static __device__ __forceinline__ void pin_i(int& x) {
  asm volatile("" : "+v"(x));
}
static __device__ __forceinline__ const bf16* pin_p(const bf16* p) {
  uint64_t u = (uint64_t)(uintptr_t)p;
  asm volatile("" : "+v"(u));
  return (const bf16*)(uintptr_t)u;
}

// ---------------- merged prep: x -> bf16 (blocks 0..3071) and
// weights -> bf16 transposed [n][k] (blocks 3072..3791) ----------------
__global__ __launch_bounds__(256) void k_prep(
    const float* __restrict__ x, bf16* __restrict__ xb,
    const float* __restrict__ w0, const float* __restrict__ w1,
    const float* __restrict__ w2, const float* __restrict__ w3,
    const float* __restrict__ w4, bf16* __restrict__ wt) {
  __shared__ float tb[64][65];
  int bid = blockIdx.x;
  if (bid < 3072) {
    int i = (bid * 256 + threadIdx.x) * 4;
    float4 v = *(const float4*)(x + i);
    bf16x4 o;
    o[0] = (bf16)v.x; o[1] = (bf16)v.y; o[2] = (bf16)v.z; o[3] = (bf16)v.w;
    *(bf16x4*)(xb + i) = o;
    return;
  }
  int id = bid - 3072;
  int w = id / 144, rem = id % 144;
  int k0 = (rem / 12) * 64, n0 = (rem % 12) * 64;
  const float* src = (w == 0) ? w0 : (w == 1) ? w1 : (w == 2) ? w2 : (w == 3) ? w3 : w4;
  int tx = threadIdx.x & 63, ty = threadIdx.x >> 6;
#pragma unroll
  for (int it = 0; it < 16; ++it) {
    int r = it * 4 + ty;
    tb[r][tx] = src[(size_t)(k0 + r) * nD + n0 + tx];
  }
  __syncthreads();
  bf16* dst = wt + (size_t)w * nD * nD;
#pragma unroll
  for (int it = 0; it < 8; ++it) {
    int r2 = it * 8 + ty * 2 + (tx >> 5);
    int k2 = (tx & 31) * 2;
    bf16x2 val;
    val[0] = (bf16)tb[k2][r2];
    val[1] = (bf16)tb[k2 + 1][r2];
    *(bf16x2*)(dst + (size_t)(n0 + r2) * nD + k0 + k2) = val;
  }
}

// ---------------- QPKV GEMM: C = X @ W (Wt is W^T), 128x128 tile, BK=64 ----------------
// Single-buffered m97 structure, 32KB LDS, 3 blocks/CU, XCD swizzle.
// Hoisted offsets/pointers PINNED in VGPRs (anti-rematerialization).
__global__ __launch_bounds__(256, 3) void k_gemm_qpkv(
    const bf16* __restrict__ xb, const bf16* __restrict__ wt,
    bf16* __restrict__ qf, bf16* __restrict__ pf, bf16* __restrict__ kf_,
    bf16* __restrict__ vt) {
  __shared__ alignas(16) char smem[32768];  // A 16K | B 16K
  int t = threadIdx.x, lane = t & 63, w = t >> 6;
  int fr = lane & 15, fg = lane >> 4;
  int wm = w >> 1, wn = w & 1;
  int p = blockIdx.x;
  int xcd = p & 7, slot = p >> 3;          // slot 0..95
  int combo = (xcd & 3) * 6 + (slot >> 4); // 0..23 = (n-col, widx)
  int yy = (xcd >> 2) * 16 + (slot & 15);  // 0..31 = m-row block
  int xx = combo % 6, widx = combo / 6;
  int m0 = yy * 128, n0 = xx * 128;
  const bf16* abase = xb + (size_t)m0 * nD;
  const bf16* bbase = wt + (size_t)widx * nD * nD + (size_t)n0 * nD;

  f32x4 acc[4][4];
#pragma unroll
  for (int i = 0; i < 4; ++i)
#pragma unroll
    for (int j = 0; j < 4; ++j) acc[i][j] = (f32x4){0.f, 0.f, 0.f, 0.f};

  int aoff[2][4], boff[2][4];
#pragma unroll
  for (int ks = 0; ks < 2; ++ks) {
#pragma unroll
    for (int i = 0; i < 4; ++i) {
      int row = wm * 64 + i * 16 + fr;
      aoff[ks][i] = row * 128 + (((ks * 4 + fg) ^ (row & 7)) << 4);
      pin_i(aoff[ks][i]);
      int rowb = wn * 64 + i * 16 + fr;
      boff[ks][i] = 16384 + rowb * 128 + (((ks * 4 + fg) ^ (rowb & 7)) << 4);
      pin_i(boff[ks][i]);
    }
  }
  const bf16 *asrc[4], *bsrc[4];
#pragma unroll
  for (int i = 0; i < 4; ++i) {
    int row = i * 32 + (t >> 3);
    int c = (t & 7) ^ (row & 7);
    asrc[i] = pin_p(abase + (size_t)row * nD + c * 8);
    bsrc[i] = pin_p(bbase + (size_t)row * nD + c * 8);
  }

#pragma unroll 1
  for (int kt = 0; kt < 12; ++kt) {
#pragma unroll
    for (int i = 0; i < 4; ++i) {
      gll16(asrc[i] + kt * 64, smem + i * 4096 + w * 1024);
      gll16(bsrc[i] + kt * 64, smem + 16384 + i * 4096 + w * 1024);
    }
    __syncthreads();
#pragma unroll
    for (int ks = 0; ks < 2; ++ks) {
      bf16x8 af[4], bfr[4];
#pragma unroll
      for (int i = 0; i < 4; ++i)
        af[i] = *(const bf16x8*)(smem + aoff[ks][i]);
#pragma unroll
      for (int j = 0; j < 4; ++j)
        bfr[j] = *(const bf16x8*)(smem + boff[ks][j]);
#pragma unroll
      for (int i = 0; i < 4; ++i)
#pragma unroll
        for (int j = 0; j < 4; ++j) acc[i][j] = mfma16(af[i], bfr[j], acc[i][j]);
    }
    __syncthreads();
  }

  if (widx < 3) {
    bf16* outf = (widx == 0) ? qf : (widx == 1) ? pf : kf_;
    float oscale = (widx == 2) ? 0.18033688f : 1.0f;  // K: DK^-0.5 * log2(e)
#pragma unroll
    for (int i = 0; i < 4; ++i)
#pragma unroll
      for (int j = 0; j < 4; ++j) {
        int n = n0 + wn * 64 + j * 16 + fr;
#pragma unroll
        for (int r = 0; r < 4; ++r) {
          int m = m0 + wm * 64 + i * 16 + fg * 4 + r;
          outf[(size_t)m * nD + n] = (bf16)(acc[i][j][r] * oscale);
        }
      }
  } else {
#pragma unroll
    for (int i = 0; i < 4; ++i)
#pragma unroll
      for (int j = 0; j < 4; ++j) {
        int n = n0 + wn * 64 + j * 16 + fr;
        int h = n >> 6, dk = n & 63;
        int mbase = m0 + wm * 64 + i * 16 + fg * 4;
        int b = mbase >> 11, s = mbase & (nS - 1);
        int bh = b * nH + h;
        bf16x4 pk;
#pragma unroll
        for (int r = 0; r < 4; ++r) pk[r] = (bf16)acc[i][j][r];
        *(bf16x4*)(vt + ((size_t)bh * nDK + dk) * nS + s) = pk;
      }
  }
}

// ---------------- attention pass 1 + leapfrog -> q_new ----------------
// R13 structure; hoisted LDS offsets + staging pointers PINNED in VGPRs so
// the compiler cannot rematerialize the addressing inside the K-loop.
__global__ __launch_bounds__(256, 3) void k_attn(
    const bf16* __restrict__ qf, const bf16* __restrict__ pf,
    const bf16* __restrict__ kf_, const bf16* __restrict__ vt,
    const float* __restrict__ dtp, const float* __restrict__ gatep,
    bf16* __restrict__ qn) {
  // LDS: K dbuf @0/@8192 | V dbuf @16384/@24576 | P 4x2KB @32768  = 40KB
  __shared__ alignas(16) char lds[40960];
  int t = threadIdx.x, lane = t & 63, w = t >> 6;
  int fr = lane & 15, fg = lane >> 4;
  int p = blockIdx.x;
  int xcd = p & 7, slot = p >> 3;
  int qt = slot & 31, bh = xcd + 8 * (slot >> 5);
  int b = bh / nH, h = bh % nH;
  int q0 = qt * 64 + w * 16;
  const bf16* Qrow = qf + (size_t)(b * nS) * nD + (size_t)h * nDK;
  const bf16* Prow = pf + (size_t)(b * nS) * nD + (size_t)h * nDK;
  const bf16* Krow = kf_ + (size_t)(b * nS) * nD + (size_t)h * nDK;
  const bf16* Vb = vt + (size_t)bh * nDK * nS;
  char* myp = lds + 32768 + w * 2048;

  bf16x8 qa[2];
#pragma unroll
  for (int ks = 0; ks < 2; ++ks)
    qa[ks] = *(const bf16x8*)(Qrow + (size_t)(q0 + fr) * nD + ks * 32 + fg * 8);

  bf16x8 vone;
#pragma unroll
  for (int i = 0; i < 8; ++i) vone[i] = (bf16)1.0f;

  f32x4 o[5];  // o[0..3]: O^T[dv=df*16+fg*4+r][q=fr]; o[4]: row-sum lr
#pragma unroll
  for (int df = 0; df < 5; ++df) o[df] = (f32x4){0.f, 0.f, 0.f, 0.f};

  int koA[4], koB[4];
#pragma unroll
  for (int kfi = 0; kfi < 4; ++kfi) {
    int key = kfi * 16 + fr;
    koA[kfi] = key * 128 + ((fg ^ (key & 7)) << 4);
    pin_i(koA[kfi]);
    koB[kfi] = key * 128 + (((4 + fg) ^ (key & 7)) << 4);
    pin_i(koB[kfi]);
  }
  int vo[2][4], pr[2], pw[4];
#pragma unroll
  for (int ks = 0; ks < 2; ++ks) {
    pr[ks] = fr * 128 + (((ks * 4 + fg) ^ (fr & 7)) << 4);
    pin_i(pr[ks]);
#pragma unroll
    for (int df = 0; df < 4; ++df) {
      int row = df * 16 + fr;
      vo[ks][df] = row * 128 + (((ks * 4 + fg) ^ (row & 7)) << 4);
      pin_i(vo[ks][df]);
    }
  }
#pragma unroll
  for (int kfi = 0; kfi < 4; ++kfi) {
    int blk16 = kfi * 2 + (fg >> 1);
    pw[kfi] = fr * 128 + (((blk16 ^ (fr & 7)) << 4) | ((fg & 1) << 3));
    pin_i(pw[kfi]);
  }

  const bf16 *ks0, *ks1, *vs0, *vs1;
  {
    int r0 = w * 16 + (lane >> 3), c0 = (lane & 7) ^ (r0 & 7);
    int r1 = r0 + 8, c1 = (lane & 7) ^ (r1 & 7);
    ks0 = pin_p(Krow + (size_t)r0 * nD + c0 * 8);
    ks1 = pin_p(Krow + (size_t)r1 * nD + c1 * 8);
    vs0 = pin_p(Vb + (size_t)r0 * nS + c0 * 8);
    vs1 = pin_p(Vb + (size_t)r1 * nS + c1 * 8);
  }

#define STAGE(KB, VB, kt)                                                      \
  {                                                                            \
    gll16(ks0 + (size_t)(kt)*64 * nD, lds + (KB) + w * 2048);                  \
    gll16(vs0 + (kt)*64, lds + (VB) + w * 2048);                               \
    gll16(ks1 + (size_t)(kt)*64 * nD, lds + (KB) + w * 2048 + 1024);           \
    gll16(vs1 + (kt)*64, lds + (VB) + w * 2048 + 1024);                        \
  }

#define COMPUTE(KB, VB)                                                        \
  {                                                                            \
    f32x4 sf[4];                                                               \
    _Pragma("unroll") for (int kfi = 0; kfi < 4; ++kfi) {                      \
      bf16x8 ka = *(const bf16x8*)(lds + (KB) + koA[kfi]);                     \
      bf16x8 kc = *(const bf16x8*)(lds + (KB) + koB[kfi]);                     \
      f32x4 s = mfma16(ka, qa[0], (f32x4){0.f, 0.f, 0.f, 0.f});                \
      sf[kfi] = mfma16(kc, qa[1], s);                                          \
    }                                                                          \
    _Pragma("unroll") for (int kfi = 0; kfi < 4; ++kfi) {                      \
      bf16x4 pk;                                                               \
      _Pragma("unroll") for (int r = 0; r < 4; ++r)                            \
          pk[r] = (bf16)__builtin_exp2f(sf[kfi][r]);                           \
      *(bf16x4*)(myp + pw[kfi]) = pk;                                          \
    }                                                                          \
    _Pragma("unroll") for (int ks = 0; ks < 2; ++ks) {                         \
      bf16x8 pb = *(const bf16x8*)(myp + pr[ks]);                              \
      _Pragma("unroll") for (int df = 0; df < 4; ++df) {                       \
        bf16x8 vv = *(const bf16x8*)(lds + (VB) + vo[ks][df]);                 \
        o[df] = mfma16(vv, pb, o[df]);                                         \
      }                                                                        \
      o[4] = mfma16(vone, pb, o[4]);                                           \
    }                                                                          \
  }

#define VMCNT4 asm volatile("s_waitcnt vmcnt(4)" ::: "memory")
#define VMCNT0 asm volatile("s_waitcnt vmcnt(0)" ::: "memory")
#define BAR __builtin_amdgcn_s_barrier()

  STAGE(0, 16384, 0);
#pragma unroll 1
  for (int kt = 0; kt < 32; kt += 2) {
    STAGE(8192, 24576, kt + 1);  // prefetch stays in flight across barrier
    VMCNT4;                      // wait current buf's 4 loads only
    BAR;
    COMPUTE(0, 16384);
    BAR;
    if (kt + 2 < 32) {
      STAGE(0, 16384, kt + 2);
      VMCNT4;
    } else {
      VMCNT0;
    }
    BAR;
    COMPUTE(8192, 24576);
    BAR;
  }
#undef STAGE
#undef COMPUTE
#undef VMCNT4
#undef VMCNT0
#undef BAR

  // leapfrog: q_new = q + dt*p - (dt^2/2)*gate*pe1
  float dt = dtp[0], gate = gatep[0];
  float c2 = 0.5f * dt * dt * gate;
  float inv = 1.f / o[4][0];  // lr, identical in every lane sharing this q
  int qrow = q0 + fr;
#pragma unroll
  for (int df = 0; df < 4; ++df) {
    int dk = df * 16 + fg * 4;
    bf16x4 qv4 = *(const bf16x4*)(Qrow + (size_t)qrow * nD + dk);
    bf16x4 pv4 = *(const bf16x4*)(Prow + (size_t)qrow * nD + dk);
    bf16x4 ov;
#pragma unroll
    for (int r = 0; r < 4; ++r) {
      float pe = o[df][r] * inv;
      ov[r] = (bf16)((float)qv4[r] + dt * (float)pv4[r] - c2 * pe);
    }
    *(bf16x4*)(qn + ((size_t)(b * nS) + qrow) * nD + h * nDK + dk) = ov;
  }
}

// ---------------- output GEMM: gw = bf16(qn @ Wo)  (bias+residual in LN) ----------------
// 64x128 tiles, grid 384, single-buffered 24KB, (256,3), XCD swizzle, pinned.
__global__ __launch_bounds__(256, 3) void k_gemm_out(
    const bf16* __restrict__ qn, const bf16* __restrict__ wto,
    bf16* __restrict__ gw) {
  __shared__ alignas(16) char smem[24576];
  int t = threadIdx.x, lane = t & 63, w = t >> 6;
  int fr = lane & 15, fg = lane >> 4;
  int wm = w >> 1, wn = w & 1;  // wm: 32-row half, wn: 64-col half
  int p = blockIdx.x;
  int xcd = p & 7, slot = p >> 3;       // slot 0..47
  int by = xcd * 8 + slot / 6;          // 0..63 m-block (contig per XCD)
  int bx = slot % 6;                    // 0..5 n-block
  int m0 = by * 64, n0 = bx * 128;
  const bf16* abase = qn + (size_t)m0 * nD;
  const bf16* bbase = wto + (size_t)n0 * nD;

  f32x4 acc[2][4];
#pragma unroll
  for (int i = 0; i < 2; ++i)
#pragma unroll
    for (int j = 0; j < 4; ++j) acc[i][j] = (f32x4){0.f, 0.f, 0.f, 0.f};

  int aoff[2][2], boff[2][4];
#pragma unroll
  for (int ks = 0; ks < 2; ++ks) {
#pragma unroll
    for (int i = 0; i < 2; ++i) {
      int row = wm * 32 + i * 16 + fr;
      aoff[ks][i] = row * 128 + (((ks * 4 + fg) ^ (row & 7)) << 4);
      pin_i(aoff[ks][i]);
    }
#pragma unroll
    for (int j = 0; j < 4; ++j) {
      int rowb = wn * 64 + j * 16 + fr;
      boff[ks][j] = 8192 + rowb * 128 + (((ks * 4 + fg) ^ (rowb & 7)) << 4);
      pin_i(boff[ks][j]);
    }
  }
  const bf16 *asrc[2], *bsrc[4];
#pragma unroll
  for (int i = 0; i < 2; ++i) {
    int row = w * 16 + i * 8 + (lane >> 3);
    int c = (lane & 7) ^ (row & 7);
    asrc[i] = pin_p(abase + (size_t)row * nD + c * 8);
  }
#pragma unroll
  for (int i = 0; i < 4; ++i) {
    int row = w * 32 + i * 8 + (lane >> 3);
    int c = (lane & 7) ^ (row & 7);
    bsrc[i] = pin_p(bbase + (size_t)row * nD + c * 8);
  }

#pragma unroll 1
  for (int kt = 0; kt < 12; ++kt) {
#pragma unroll
    for (int i = 0; i < 2; ++i)
      gll16(asrc[i] + kt * 64, smem + w * 2048 + i * 1024);
#pragma unroll
    for (int i = 0; i < 4; ++i)
      gll16(bsrc[i] + kt * 64, smem + 8192 + w * 4096 + i * 1024);
    __syncthreads();
#pragma unroll
    for (int ks = 0; ks < 2; ++ks) {
      bf16x8 af[2], bfr[4];
#pragma unroll
      for (int i = 0; i < 2; ++i)
        af[i] = *(const bf16x8*)(smem + aoff[ks][i]);
#pragma unroll
      for (int j = 0; j < 4; ++j)
        bfr[j] = *(const bf16x8*)(smem + boff[ks][j]);
#pragma unroll
      for (int i = 0; i < 2; ++i)
#pragma unroll
        for (int j = 0; j < 4; ++j) acc[i][j] = mfma16(af[i], bfr[j], acc[i][j]);
    }
    __syncthreads();
  }

#pragma unroll
  for (int i = 0; i < 2; ++i)
#pragma unroll
    for (int j = 0; j < 4; ++j) {
      int n = n0 + wn * 64 + j * 16 + fr;
#pragma unroll
      for (int r = 0; r < 4; ++r) {
        int m = m0 + wm * 32 + i * 16 + fg * 4 + r;
        gw[(size_t)m * nD + n] = (bf16)acc[i][j][r];
      }
    }
}

// ---------------- LayerNorm: y = LN(gw + bo + x) * gamma + beta ----------------
__global__ __launch_bounds__(256) void k_ln(const bf16* __restrict__ gw,
                                            const float* __restrict__ bo,
                                            const float* __restrict__ x,
                                            const float* __restrict__ gamma,
                                            const float* __restrict__ beta,
                                            float* __restrict__ y) {
  int t = threadIdx.x, lane = t & 63, w = t >> 6;
  int row = blockIdx.x * 4 + w;
  const bf16* gp = gw + (size_t)row * nD;
  const float* xp = x + (size_t)row * nD;
  float2 v[6];
  float s1 = 0.f, s2 = 0.f;
#pragma unroll
  for (int i = 0; i < 6; ++i) {
    int col = i * 128 + lane * 2;
    bf16x2 g2 = *(const bf16x2*)(gp + col);
    float2 x2 = *(const float2*)(xp + col);
    float2 b2 = *(const float2*)(bo + col);
    float v0 = (float)g2[0] + x2.x + b2.x;
    float v1 = (float)g2[1] + x2.y + b2.y;
    v[i].x = v0;
    v[i].y = v1;
    s1 += v0 + v1;
    s2 += v0 * v0 + v1 * v1;
  }
#pragma unroll
  for (int d = 1; d < 64; d <<= 1) {
    s1 += __shfl_xor(s1, d);
    s2 += __shfl_xor(s2, d);
  }
  float mu = s1 * (1.f / 768.f);
  float var = s2 * (1.f / 768.f) - mu * mu;
  float rstd = rsqrtf(var + LN_EPS);
  float* yp = y + (size_t)row * nD;
#pragma unroll
  for (int i = 0; i < 6; ++i) {
    int col = i * 128 + lane * 2;
    float2 g2 = *(const float2*)(gamma + col);
    float2 be = *(const float2*)(beta + col);
    float2 o;
    o.x = (v[i].x - mu) * rstd * g2.x + be.x;
    o.y = (v[i].y - mu) * rstd * g2.y + be.y;
    *(float2*)(yp + col) = o;
  }
}

extern "C" void kernel_launch(void* const* d_in, const int* in_sizes, int n_in,
                              void* d_out, int out_size, void* d_ws, size_t ws_size,
                              hipStream_t stream) {
  const float* x = (const float*)d_in[0];
  const float* Wq = (const float*)d_in[1];
  const float* Wp = (const float*)d_in[2];
  const float* Wk = (const float*)d_in[3];
  const float* Wv = (const float*)d_in[4];
  const float* Wo = (const float*)d_in[5];
  const float* bo = (const float*)d_in[6];
  const float* gamma = (const float*)d_in[7];
  const float* beta = (const float*)d_in[8];
  const float* dt = (const float*)d_in[9];
  const float* gate = (const float*)d_in[10];

  char* ws = (char*)d_ws;
  const size_t szb = (size_t)nM * nD * 2;  // 6,291,456 bytes per bf16 [4096][768]
  bf16* xb = (bf16*)(ws + 0 * szb);        // reused as qn after QPKV GEMM
  bf16* qf = (bf16*)(ws + 1 * szb);        // reused as gw after attn
  bf16* pf = (bf16*)(ws + 2 * szb);
  bf16* kf_ = (bf16*)(ws + 3 * szb);
  bf16* vt = (bf16*)(ws + 4 * szb);
  bf16* wt = (bf16*)(ws + 5 * szb);  // 5 * 768*768 bf16 = 5,898,240 bytes
  bf16* qn = xb;
  bf16* gw = qf;  // qf dead after attn

  k_prep<<<dim3(3792), dim3(256), 0, stream>>>(x, xb, Wq, Wp, Wk, Wv, Wo, wt);
  k_gemm_qpkv<<<dim3(768), dim3(256), 0, stream>>>(xb, wt, qf, pf, kf_, vt);
  k_attn<<<dim3(768), dim3(256), 0, stream>>>(qf, pf, kf_, vt, dt, gate, qn);
  k_gemm_out<<<dim3(384), dim3(256), 0, stream>>>(qn, wt + 4 * (size_t)nD * nD, gw);
  k_ln<<<dim3(nM / 4), dim3(256), 0, stream>>>(gw, bo, x, gamma, beta, (float*)d_out);
}